// Round 1
// 21353.549 us; speedup vs baseline: 1.7876x; 1.7876x over previous
//
#include <hip/hip_runtime.h>
#include <hip/hip_bf16.h>

// MultilayerGRU: B=32 S=512 I=H=O=1024 L=3.
// Round 5: kill the cache-maintenance storm.
//  - act state packed (hi<<16|lo) u32, accessed via RELAXED agent atomics
//    (global_load/store sc1 -> device-coherent through L3, no buffer_inv needed)
//  - flag poll with RELAXED loads (acquire-per-poll emitted buffer_inv sc1 =
//    full L2 invalidate per iteration -> L2 pipeline saturation; removed)
//  - __threadfence() (per-wave wbl2+inv) removed; single RELEASE store from
//    tid 0 publishes (wbl2 covers the few plain dout/stfin lines)

#define NB 32
#define NS 512
#define NI 1024
#define NH 1024
#define NL 3
#define NO 1024

#define WGN 256
#define BLK 512
#define SLOTS 12
#define RPB 2096                 // weight row pitch bytes; 524 dwords == 12 mod 32 -> 2-way max (free)
#define ZROW 72                  // zero-row index
#define COFF (73 * RPB)          // 153,008
#define CPITCH 33                // 33 dwords == 1 mod 32 -> conflict-free
#define LDSB (COFF + 48 * CPITCH * 4)   // 159,344 <= 163,840

using short8 = __attribute__((ext_vector_type(8))) short;
using floatx4 = __attribute__((ext_vector_type(4))) float;

static __device__ __forceinline__ float bf2f(unsigned short u) {
    union { unsigned int i; float f; } v;
    v.i = ((unsigned int)u) << 16;
    return v.f;
}

static __device__ __forceinline__ unsigned short f2bf(float f) {
    __hip_bfloat16 h = __float2bfloat16(f);   // RNE
    union { __hip_bfloat16 h; unsigned short u; } v;
    v.h = h;
    return v.u;
}

static __device__ __forceinline__ void load8h(const unsigned short* p, float w[8]) {
    uint4 q = *(const uint4*)p;
    unsigned int u[4] = {q.x, q.y, q.z, q.w};
#pragma unroll
    for (int i = 0; i < 4; ++i) {
        w[2*i]   = __uint_as_float(u[i] << 16);
        w[2*i+1] = __uint_as_float(u[i] & 0xffff0000u);
    }
}

static __device__ __forceinline__ void load8f(const float* p, float w[8]) {
    float4 a = *(const float4*)p;
    float4 b = *(const float4*)(p + 4);
    w[0]=a.x; w[1]=a.y; w[2]=a.z; w[3]=a.w;
    w[4]=b.x; w[5]=b.y; w[6]=b.z; w[7]=b.w;
}

// ---------------- dtype detection ----------------
__global__ void detect_kernel(const unsigned int* __restrict__ xw, int* __restrict__ flag) {
    __shared__ int cnt[256];
    int c = 0;
    for (int i = threadIdx.x; i < 1024; i += 256) {
        unsigned int e = (xw[i] >> 7) & 0xFFu;
        if (e >= 0x78u && e <= 0x84u) c++;
    }
    cnt[threadIdx.x] = c;
    __syncthreads();
    if (threadIdx.x == 0) {
        int s = 0;
        for (int i = 0; i < 256; ++i) s += cnt[i];
        *flag = (s < 512) ? 1 : 0;
    }
}

// ---------------- init: h0 -> act parity-1 packed (hi<<16|lo); zero flags ----
__global__ void init_act(const void* __restrict__ h0,
                         unsigned int* __restrict__ act,
                         unsigned int* __restrict__ gflags,
                         const int* __restrict__ flagp) {
    const int f32m = *flagp;
    const int idx = blockIdx.x * 256 + threadIdx.x;  // l*32768 + b*1024 + j
    if (idx < WGN * 32) gflags[idx] = 0u;
    if (idx >= NL * NB * NH) return;
    const int l = idx >> 15;
    const int b = (idx >> 10) & 31;
    const int j = idx & 1023;
    const size_t src = (size_t)b * NL * NH + (size_t)l * NH + j;
    float v = f32m ? ((const float*)h0)[src] : bf2f(((const unsigned short*)h0)[src]);
    unsigned short hi = f2bf(v);
    unsigned short lo = f2bf(v - bf2f(hi));
    const size_t dst = ((size_t)(l * 2 + 1) * NB + b) * NH + j;   // parity 1
    act[dst] = ((unsigned int)hi << 16) | lo;
}

// ---------------- persistent pipeline kernel ----------------
__global__ __launch_bounds__(BLK, 2) void gru_persist(
    const void* __restrict__ x,
    const void* __restrict__ Wzi_, const void* __restrict__ Wzh_, const void* __restrict__ bzh_,
    const void* __restrict__ Wri_, const void* __restrict__ Wrh_, const void* __restrict__ brh_,
    const void* __restrict__ Wgi_, const void* __restrict__ Wgh_, const void* __restrict__ bgh_,
    void* __restrict__ dout,
    unsigned int* __restrict__ act,
    float* __restrict__ stfin,
    const int* __restrict__ flagp,
    unsigned int* __restrict__ gflags)
{
    extern __shared__ char lds[];
    float* clds = (float*)(lds + COFF);

    const int f32m = *flagp;
    const int tid  = threadIdx.x;
    const int wg   = blockIdx.x;
    const int lane = tid & 63;
    const int wid  = tid >> 6;          // 0..7
    const int Mtile = wid & 1;
    const int khalf = wid >> 1;         // 0..3 -> 256-col K slice
    const int n16  = lane & 15;
    const int q4   = lane >> 4;

    const int slot0 = wg * SLOTS;

    // ---- preload weights into LDS (bf16) ----
    {
        const void* Wmats[6] = {Wzi_, Wzh_, Wri_, Wrh_, Wgi_, Wgh_};
        if (f32m) {
            for (int idx = tid; idx < 72 * 256; idx += BLK) {
                const int r = idx >> 8, c4 = (idx & 255) * 4;
                const int slot = slot0 + r / 6, g = r % 6;
                const int layer = slot >> 10, j = slot & 1023;
                const float* src = (const float*)Wmats[g] + (size_t)layer * NH * NI + (size_t)j * NI + c4;
                float4 f = *(const float4*)src;
                unsigned short* dst = (unsigned short*)(lds + r * RPB + c4 * 2);
                dst[0] = f2bf(f.x); dst[1] = f2bf(f.y); dst[2] = f2bf(f.z); dst[3] = f2bf(f.w);
            }
        } else {
            for (int idx = tid; idx < 72 * 128; idx += BLK) {
                const int r = idx >> 7, c8 = (idx & 127) * 8;
                const int slot = slot0 + r / 6, g = r % 6;
                const int layer = slot >> 10, j = slot & 1023;
                const unsigned short* src = (const unsigned short*)Wmats[g] + (size_t)layer * NH * NI + (size_t)j * NI + c8;
                *(uint4*)(lds + r * RPB + c8 * 2) = *(const uint4*)src;
            }
        }
        unsigned int* z = (unsigned int*)(lds + ZROW * RPB);
        for (int c = tid; c < RPB / 4; c += BLK) z[c] = 0u;
    }

    // ---- epilogue thread state (tid < 384): biases + register h_prev ----
    int eci = 0, eb = 0, elg = 0, ej = 0;
    float ebz = 0.f, ebr = 0.f, ebg = 0.f, ehp = 0.f;
    if (tid < NB * SLOTS) {
        eci = tid % SLOTS; eb = tid / SLOTS;
        const int slot = slot0 + eci;
        elg = slot >> 10; ej = slot & 1023;
        const size_t bidx = (size_t)elg * NH + ej;
        if (f32m) {
            ebz = ((const float*)bzh_)[bidx];
            ebr = ((const float*)brh_)[bidx];
            ebg = ((const float*)bgh_)[bidx];
        } else {
            ebz = bf2f(((const unsigned short*)bzh_)[bidx]);
            ebr = bf2f(((const unsigned short*)brh_)[bidx]);
            ebg = bf2f(((const unsigned short*)bgh_)[bidx]);
        }
    }

    // ---- layer groups (slot range may straddle one layer boundary) ----
    const int lay0 = slot0 >> 10;
    const int lay1 = (slot0 + SLOTS - 1) >> 10;
    const int ngroups = (lay0 == lay1) ? 1 : 2;
    const int n0 = (ngroups == 1) ? SLOTS : (1024 - (slot0 & 1023));

    __syncthreads();

    for (int s = 0; s < NS + NL - 1; ++s) {
        for (int i = tid; i < 48 * CPITCH; i += BLK) clds[i] = 0.f;
        __syncthreads();

        floatx4 acc[3];
#pragma unroll
        for (int nt = 0; nt < 3; ++nt) acc[nt] = (floatx4){0.f, 0.f, 0.f, 0.f};

        for (int grp = 0; grp < ngroups; ++grp) {
            const int lg = (grp == 0) ? lay0 : lay1;
            const int t = s - lg;
            if (t < 0 || t >= NS) continue;
            const int ntLo = (grp == 0) ? 0 : ((4 * n0) >> 4);
            const int ntHi = (grp == 0) ? (ngroups == 1 ? 2 : ((4 * n0) >> 4) - 1) : 2;
            const int mb = Mtile * 16 + n16;

            for (int phase = 0; phase < 2; ++phase) {
                int brow[3];
#pragma unroll
                for (int nt = 0; nt < 3; ++nt) {
                    const int v = nt * 16 + n16;
                    const int ci = v >> 2, g = v & 3;
                    int r;
                    if (phase == 0) r = (g == 3) ? ZROW : ci * 6 + ((g == 2) ? 4 : g * 2);
                    else            r = (g == 2) ? ZROW : ci * 6 + ((g == 3) ? 5 : g * 2 + 1);
                    brow[nt] = r;
                }

                const bool isx = (phase == 0 && lg == 0);
                const bool dolo = isx ? (f32m != 0) : true;

                // hoist all A-frags for this phase into registers
                short8 AH[8], AL[8];
                if (isx) {
                    if (f32m) {
                        const float* xb = (const float*)x + ((size_t)mb * NS + t) * NI + khalf * 256 + q4 * 8;
#pragma unroll
                        for (int ks = 0; ks < 8; ++ks) {
                            float f[8];
                            load8f(xb + ks * 32, f);
#pragma unroll
                            for (int e = 0; e < 8; ++e) {
                                unsigned short h = f2bf(f[e]);
                                AH[ks][e] = (short)h;
                                AL[ks][e] = (short)f2bf(f[e] - bf2f(h));
                            }
                        }
                    } else {
                        const unsigned short* xb = (const unsigned short*)x + ((size_t)mb * NS + t) * NI + khalf * 256 + q4 * 8;
#pragma unroll
                        for (int ks = 0; ks < 8; ++ks)
                            AH[ks] = *(const short8*)(xb + ks * 32);
                    }
                } else {
                    const int src_l = (phase == 0) ? lg - 1 : lg;
                    const int src_p = (phase == 0) ? (t & 1) : ((t - 1) & 1);
                    const size_t ab = ((size_t)(src_l * 2 + src_p) * NB + mb) * NH + khalf * 256 + q4 * 8;
                    const unsigned long long* ap = (const unsigned long long*)(act + ab);
                    // issue all 32 L3-coherent loads first, then unpack
                    unsigned long long qq[8][4];
#pragma unroll
                    for (int ks = 0; ks < 8; ++ks)
#pragma unroll
                        for (int i = 0; i < 4; ++i)
                            qq[ks][i] = __hip_atomic_load(ap + (size_t)ks * 16 + i,
                                                          __ATOMIC_RELAXED, __HIP_MEMORY_SCOPE_AGENT);
#pragma unroll
                    for (int ks = 0; ks < 8; ++ks) {
#pragma unroll
                        for (int i = 0; i < 4; ++i) {
                            const unsigned int c0 = (unsigned int)qq[ks][i];
                            const unsigned int c1 = (unsigned int)(qq[ks][i] >> 32);
                            AH[ks][2*i]   = (short)(c0 >> 16);
                            AL[ks][2*i]   = (short)(c0 & 0xffffu);
                            AH[ks][2*i+1] = (short)(c1 >> 16);
                            AL[ks][2*i+1] = (short)(c1 & 0xffffu);
                        }
                    }
                }

#pragma unroll
                for (int ks = 0; ks < 8; ++ks) {
                    const int k0 = khalf * 256 + ks * 32;
#pragma unroll
                    for (int nt = 0; nt < 3; ++nt) {
                        if (nt < ntLo || nt > ntHi) continue;
                        const short8 bf = *(const short8*)(lds + brow[nt] * RPB + k0 * 2 + q4 * 16);
                        acc[nt] = __builtin_amdgcn_mfma_f32_16x16x32_bf16(AH[ks], bf, acc[nt], 0, 0, 0);
                        if (dolo)
                            acc[nt] = __builtin_amdgcn_mfma_f32_16x16x32_bf16(AL[ks], bf, acc[nt], 0, 0, 0);
                    }
                }
            }
        }

        // dump accumulators (C/D: col=lane&15, row=q4*4+reg)
        {
            const int mbase = Mtile * 16 + q4 * 4;
#pragma unroll
            for (int nt = 0; nt < 3; ++nt) {
                const int vcol = nt * 16 + n16;
#pragma unroll
                for (int r = 0; r < 4; ++r)
                    atomicAdd(&clds[vcol * CPITCH + mbase + r], acc[nt][r]);
            }
        }
        __syncthreads();

        // epilogue: one thread per (col, batch)
        if (tid < NB * SLOTS) {
            const int t = s - elg;
            if (t >= 0 && t < NS) {
                const float zp = clds[(eci * 4 + 0) * CPITCH + eb];
                const float rp = clds[(eci * 4 + 1) * CPITCH + eb];
                const float gi = clds[(eci * 4 + 2) * CPITCH + eb];
                const float gh = clds[(eci * 4 + 3) * CPITCH + eb];
                float hp;
                if (t == 0) {
                    const size_t hoff = ((size_t)(elg * 2 + 1) * NB + eb) * NH + ej;
                    const unsigned int pv = __hip_atomic_load(&act[hoff],
                                                              __ATOMIC_RELAXED, __HIP_MEMORY_SCOPE_AGENT);
                    hp = bf2f((unsigned short)(pv >> 16)) + bf2f((unsigned short)(pv & 0xffffu));
                } else {
                    hp = ehp;
                }
                const float z = 1.f / (1.f + expf(-(zp + ebz)));
                const float r = 1.f / (1.f + expf(-(rp + ebr)));
                const float g = tanhf(gi + r * (gh + ebg));
                const float hn = z * hp + (1.f - z) * g;
                ehp = hn;
                const unsigned short hi = f2bf(hn);
                const unsigned short lo = f2bf(hn - bf2f(hi));
                const size_t woff = ((size_t)(elg * 2 + (t & 1)) * NB + eb) * NH + ej;
                __hip_atomic_store(&act[woff], ((unsigned int)hi << 16) | lo,
                                   __ATOMIC_RELAXED, __HIP_MEMORY_SCOPE_AGENT);
                if (elg == 2) {
                    const size_t o = ((size_t)eb * NS + t) * NO + ej;
                    if (f32m) ((float*)dout)[o] = hn;
                    else      ((unsigned short*)dout)[o] = f2bf(hn);
                }
                if (t == NS - 1)
                    stfin[((size_t)elg * NB + eb) * NH + ej] = hn;
            }
        }

        // ---- all-to-all flag barrier: relaxed polls (no buffer_inv),
        //      single release publish per WG (act data is sc1 -> L3-coherent) ----
        __syncthreads();   // drains each wave's sc1 stores (vmcnt 0) before publish
        if (tid == 0)
            __hip_atomic_store(&gflags[wg * 32], (unsigned int)(s + 1),
                               __ATOMIC_RELEASE, __HIP_MEMORY_SCOPE_AGENT);
        if (tid < WGN) {
            while (__hip_atomic_load(&gflags[tid * 32], __ATOMIC_RELAXED,
                                     __HIP_MEMORY_SCOPE_AGENT) <= (unsigned int)s)
                __builtin_amdgcn_s_sleep(2);
        }
        __syncthreads();
    }
}

// ---------------- fallback kernels (round-2, proven) ----------------
__global__ void init_kernel(const void* __restrict__ h0, float* __restrict__ st,
                            const int* __restrict__ flagp) {
    const int f32m = *flagp;
    const int idx = blockIdx.x * 256 + threadIdx.x;
    if (idx >= NL * NB * NH) return;
    const int l = idx >> 15;
    const int b = (idx >> 10) & 31;
    const int j = idx & 1023;
    const size_t src = (size_t)b * NL * NH + (size_t)l * NH + j;
    st[idx] = f32m ? ((const float*)h0)[src] : bf2f(((const unsigned short*)h0)[src]);
}

__global__ __launch_bounds__(256) void gru_layer(
    const void*  __restrict__ x,
    const float* __restrict__ inp,
    const float* __restrict__ hprev,
    float*       __restrict__ hnew,
    void*        __restrict__ h2out,
    const void* __restrict__ Wzi_, const void* __restrict__ Wzh_, const void* __restrict__ bzh_,
    const void* __restrict__ Wri_, const void* __restrict__ Wrh_, const void* __restrict__ brh_,
    const void* __restrict__ Wgi_, const void* __restrict__ Wgh_, const void* __restrict__ bgh_,
    const int* __restrict__ flagp, int tl, int isX)
{
    __shared__ float s_in[NB][129];
    __shared__ float s_h [NB][129];
    __shared__ float s_red[256][6];

    const int f32m = *flagp;
    const int t = tl & 0xFFFF;
    const int l = tl >> 16;
    const int tid = threadIdx.x;
    const int b   = tid & 31;
    const int jl  = (tid >> 5) & 1;
    const int ks  = tid >> 6;
    const int j   = blockIdx.x * 2 + jl;

    const size_t wIl = (size_t)l * NH * NI + (size_t)j * NI;
    const size_t bl  = (size_t)l * NH + j;

    float azi = 0.f, azh = 0.f, ari = 0.f, arh = 0.f, agi = 0.f, agh = 0.f;

    for (int kc = 0; kc < 8; ++kc) {
        const int k0 = kc * 128;
        __syncthreads();
        for (int idx = tid; idx < NB * 128; idx += 256) {
            const int r = idx >> 7, c = idx & 127;
            float vi;
            if (isX) {
                const size_t xo = (size_t)r * NS * NI + (size_t)t * NI + (k0 + c);
                vi = f32m ? ((const float*)x)[xo] : bf2f(((const unsigned short*)x)[xo]);
            } else {
                vi = inp[r * NH + k0 + c];
            }
            s_in[r][c] = vi;
            s_h [r][c] = hprev[r * NH + k0 + c];
        }
        __syncthreads();

        const int cbase = ks * 32;
#pragma unroll
        for (int q8 = 0; q8 < 4; ++q8) {
            const int c = cbase + q8 * 8;
            const int k = k0 + c;
            float wz[8], wr[8], wg[8], vz[8], vr[8], vg[8];
            if (f32m) {
                load8f((const float*)Wzi_ + wIl + k, wz);
                load8f((const float*)Wri_ + wIl + k, wr);
                load8f((const float*)Wgi_ + wIl + k, wg);
                load8f((const float*)Wzh_ + wIl + k, vz);
                load8f((const float*)Wrh_ + wIl + k, vr);
                load8f((const float*)Wgh_ + wIl + k, vg);
            } else {
                load8h((const unsigned short*)Wzi_ + wIl + k, wz);
                load8h((const unsigned short*)Wri_ + wIl + k, wr);
                load8h((const unsigned short*)Wgi_ + wIl + k, wg);
                load8h((const unsigned short*)Wzh_ + wIl + k, vz);
                load8h((const unsigned short*)Wrh_ + wIl + k, vr);
                load8h((const unsigned short*)Wgh_ + wIl + k, vg);
            }
            float ai[8], ah[8];
#pragma unroll
            for (int q = 0; q < 8; ++q) { ai[q] = s_in[b][c + q]; ah[q] = s_h[b][c + q]; }
#pragma unroll
            for (int q = 0; q < 8; ++q) {
                azi = fmaf(wz[q], ai[q], azi);
                ari = fmaf(wr[q], ai[q], ari);
                agi = fmaf(wg[q], ai[q], agi);
                azh = fmaf(vz[q], ah[q], azh);
                arh = fmaf(vr[q], ah[q], arh);
                agh = fmaf(vg[q], ah[q], agh);
            }
        }
    }

    s_red[tid][0] = azi; s_red[tid][1] = azh; s_red[tid][2] = ari;
    s_red[tid][3] = arh; s_red[tid][4] = agi; s_red[tid][5] = agh;
    __syncthreads();

    if (ks == 0) {
#pragma unroll
        for (int w = 1; w < 4; ++w) {
            azi += s_red[tid + 64*w][0]; azh += s_red[tid + 64*w][1];
            ari += s_red[tid + 64*w][2]; arh += s_red[tid + 64*w][3];
            agi += s_red[tid + 64*w][4]; agh += s_red[tid + 64*w][5];
        }
        const float bz = f32m ? ((const float*)bzh_)[bl] : bf2f(((const unsigned short*)bzh_)[bl]);
        const float br = f32m ? ((const float*)brh_)[bl] : bf2f(((const unsigned short*)brh_)[bl]);
        const float bg = f32m ? ((const float*)bgh_)[bl] : bf2f(((const unsigned short*)bgh_)[bl]);
        const float z = 1.f / (1.f + expf(-(azi + azh + bz)));
        const float r = 1.f / (1.f + expf(-(ari + arh + br)));
        const float g = tanhf(agi + r * (agh + bg));
        const float hp = hprev[b * NH + j];
        const float hn = z * hp + (1.f - z) * g;
        hnew[b * NH + j] = hn;
        if (h2out) {
            const size_t off = (size_t)b * NS * NO + (size_t)t * NO + j;
            if (f32m) ((float*)h2out)[off] = hn;
            else      ((unsigned short*)h2out)[off] = f2bf(hn);
        }
    }
}

__global__ __launch_bounds__(256) void out_gemm(
    void* __restrict__ out, const void* __restrict__ Wout, const void* __restrict__ bout,
    const int* __restrict__ flagp)
{
    __shared__ float s_a[8][1024];
    const int f32m = *flagp;
    const int tid = threadIdx.x;
    const size_t row0 = (size_t)blockIdx.x * 8;

    for (int idx = tid; idx < 8 * 1024; idx += 256) {
        const int r = idx >> 10, c = idx & 1023;
        const size_t off = (row0 + r) * NO + c;
        s_a[r][c] = f32m ? ((const float*)out)[off] : bf2f(((const unsigned short*)out)[off]);
    }
    __syncthreads();

    float acc[4][8];
#pragma unroll
    for (int m = 0; m < 4; ++m)
#pragma unroll
        for (int r = 0; r < 8; ++r) acc[m][r] = 0.f;

    for (int k8 = 0; k8 < 128; ++k8) {
        const int k = k8 * 8;
        float wf[4][8];
#pragma unroll
        for (int m = 0; m < 4; ++m) {
            const size_t wo = (size_t)(tid + 256*m) * NH + k;
            if (f32m) load8f((const float*)Wout + wo, wf[m]);
            else      load8h((const unsigned short*)Wout + wo, wf[m]);
        }
#pragma unroll
        for (int r = 0; r < 8; ++r) {
            float a[8];
#pragma unroll
            for (int q = 0; q < 8; ++q) a[q] = s_a[r][k + q];
#pragma unroll
            for (int m = 0; m < 4; ++m)
#pragma unroll
                for (int q = 0; q < 8; ++q)
                    acc[m][r] = fmaf(wf[m][q], a[q], acc[m][r]);
        }
    }

#pragma unroll
    for (int m = 0; m < 4; ++m) {
        const int jj = tid + 256*m;
        const float bj = f32m ? ((const float*)bout)[jj] : bf2f(((const unsigned short*)bout)[jj]);
#pragma unroll
        for (int r = 0; r < 8; ++r) {
            const size_t off = (row0 + r) * NO + jj;
            const float v = acc[m][r] + bj;
            if (f32m) ((float*)out)[off] = v;
            else      ((unsigned short*)out)[off] = f2bf(v);
        }
    }
}

__global__ void tail_kernel(const float* __restrict__ st, void* __restrict__ out,
                            const int* __restrict__ flagp)
{
    const int f32m = *flagp;
    const int idx = blockIdx.x * 256 + threadIdx.x;
    if (idx >= NL * NB * NH) return;
    const int l = idx >> 15;
    const int b = (idx >> 10) & 31;
    const int j = idx & 1023;
    const size_t dst = (size_t)NB * NS * NO + (size_t)b * NL * NH + (size_t)l * NH + j;
    if (f32m) ((float*)out)[dst] = st[idx];
    else      ((unsigned short*)out)[dst] = f2bf(st[idx]);
}

// ---------------- host ----------------
extern "C" void kernel_launch(void* const* d_in, const int* in_sizes, int n_in,
                              void* d_out, int out_size, void* d_ws, size_t ws_size,
                              hipStream_t stream)
{
    const void* x    = d_in[0];
    const void* h0   = d_in[1];
    const void* Wzi  = d_in[2];
    const void* Wzh  = d_in[3];
    const void* bzh  = d_in[4];
    const void* Wri  = d_in[5];
    const void* Wrh  = d_in[6];
    const void* brh  = d_in[7];
    const void* Wgi  = d_in[8];
    const void* Wgh  = d_in[9];
    const void* bgh  = d_in[10];
    const void* Wout = d_in[11];
    const void* bout = d_in[12];

    // ws layout
    char* w = (char*)d_ws;
    float* st            = (float*)w;                       // [2][3][32][1024] f32
    int*   flag          = (int*)(w + 786432);
    unsigned int* act    = (unsigned int*)(w + 786464);     // [3][2][32][1024] packed hi|lo, ends 1,572,896
    unsigned int* gflags = (unsigned int*)(w + 1572992);    // 256 x 128B, ends 1,605,760
    auto stp = [&](int p, int l) { return st + ((size_t)(p * NL + l)) * NB * NH; };

    detect_kernel<<<1, 256, 0, stream>>>((const unsigned int*)x, flag);
    init_act<<<(NL*NB*NH + 255)/256, 256, 0, stream>>>(h0, act, gflags, flag);

    (void)hipFuncSetAttribute((const void*)gru_persist,
                              hipFuncAttributeMaxDynamicSharedMemorySize, LDSB);
    (void)hipGetLastError();   // clear
    gru_persist<<<WGN, BLK, LDSB, stream>>>(
        x, Wzi, Wzh, bzh, Wri, Wrh, brh, Wgi, Wgh, bgh,
        d_out, act, st /* final h */, flag, gflags);
    hipError_t perr = hipGetLastError();

    if (perr != hipSuccess) {
        init_kernel<<<(NL*NB*NH + 255)/256, 256, 0, stream>>>(h0, st, flag);
        for (int t = 0; t < NS; ++t) {
            const int pr = t & 1, pw = 1 - pr;
            for (int l = 0; l < NL; ++l) {
                gru_layer<<<512, 256, 0, stream>>>(
                    x,
                    l == 0 ? st : stp(pw, l - 1),
                    stp(pr, l),
                    stp(pw, l),
                    l == 2 ? d_out : (void*)nullptr,
                    Wzi, Wzh, bzh, Wri, Wrh, brh, Wgi, Wgh, bgh,
                    flag, t | (l << 16), l == 0 ? 1 : 0);
            }
        }
    }

    out_gemm<<<NB * NS / 8, 256, 0, stream>>>(d_out, Wout, bout, flag);
    tail_kernel<<<(NL*NB*NH + 255)/256, 256, 0, stream>>>(st, d_out, flag);
}

// Round 2
// 18994.844 us; speedup vs baseline: 2.0096x; 1.1242x over previous
//
#include <hip/hip_runtime.h>
#include <hip/hip_bf16.h>

// MultilayerGRU: B=32 S=512 I=H=O=1024 L=3.
// Round 6: zero cache-maintenance steady state + low-traffic 2-hop barrier.
//  - publish store now RELAXED (release emitted buffer_wbl2 sc1 = per-WG L2
//    writeback walk, 32/XCD/step -> L2 maintenance serialization; removed.
//    act/flags are sc1 so vmcnt-drain at __syncthreads already gives L3
//    visibility; dout/stfin are covered by the end-of-kernel implicit release)
//  - all-to-all poll (256 WG x 256 lanes x 256 lines ~ 200 Greq/s of sc1 L3
//    traffic competing with act loads) replaced by master barrier: WG0's 4
//    waves poll the 256 flags, publish one generation line; all others poll
//    that single line with one lane (~128x less poll traffic, still a FULL
//    barrier: nobody advances until WG0 observed all arrivals).

#define NB 32
#define NS 512
#define NI 1024
#define NH 1024
#define NL 3
#define NO 1024

#define WGN 256
#define BLK 512
#define SLOTS 12
#define RPB 2096                 // weight row pitch bytes; 524 dwords == 12 mod 32 -> 2-way max (free)
#define ZROW 72                  // zero-row index
#define COFF (73 * RPB)          // 153,008
#define CPITCH 33                // 33 dwords == 1 mod 32 -> conflict-free
#define LDSB (COFF + 48 * CPITCH * 4)   // 159,344 <= 163,840

using short8 = __attribute__((ext_vector_type(8))) short;
using floatx4 = __attribute__((ext_vector_type(4))) float;

static __device__ __forceinline__ float bf2f(unsigned short u) {
    union { unsigned int i; float f; } v;
    v.i = ((unsigned int)u) << 16;
    return v.f;
}

static __device__ __forceinline__ unsigned short f2bf(float f) {
    __hip_bfloat16 h = __float2bfloat16(f);   // RNE
    union { __hip_bfloat16 h; unsigned short u; } v;
    v.h = h;
    return v.u;
}

static __device__ __forceinline__ void load8h(const unsigned short* p, float w[8]) {
    uint4 q = *(const uint4*)p;
    unsigned int u[4] = {q.x, q.y, q.z, q.w};
#pragma unroll
    for (int i = 0; i < 4; ++i) {
        w[2*i]   = __uint_as_float(u[i] << 16);
        w[2*i+1] = __uint_as_float(u[i] & 0xffff0000u);
    }
}

static __device__ __forceinline__ void load8f(const float* p, float w[8]) {
    float4 a = *(const float4*)p;
    float4 b = *(const float4*)(p + 4);
    w[0]=a.x; w[1]=a.y; w[2]=a.z; w[3]=a.w;
    w[4]=b.x; w[5]=b.y; w[6]=b.z; w[7]=b.w;
}

// ---------------- dtype detection ----------------
__global__ void detect_kernel(const unsigned int* __restrict__ xw, int* __restrict__ flag) {
    __shared__ int cnt[256];
    int c = 0;
    for (int i = threadIdx.x; i < 1024; i += 256) {
        unsigned int e = (xw[i] >> 7) & 0xFFu;
        if (e >= 0x78u && e <= 0x84u) c++;
    }
    cnt[threadIdx.x] = c;
    __syncthreads();
    if (threadIdx.x == 0) {
        int s = 0;
        for (int i = 0; i < 256; ++i) s += cnt[i];
        *flag = (s < 512) ? 1 : 0;
    }
}

// ---------------- init: h0 -> act parity-1 packed (hi<<16|lo); zero flags+gen ----
__global__ void init_act(const void* __restrict__ h0,
                         unsigned int* __restrict__ act,
                         unsigned int* __restrict__ gflags,
                         const int* __restrict__ flagp) {
    const int f32m = *flagp;
    const int idx = blockIdx.x * 256 + threadIdx.x;  // l*32768 + b*1024 + j
    if (idx < WGN * 32 + 32) gflags[idx] = 0u;       // 256 flag lines + gen line
    if (idx >= NL * NB * NH) return;
    const int l = idx >> 15;
    const int b = (idx >> 10) & 31;
    const int j = idx & 1023;
    const size_t src = (size_t)b * NL * NH + (size_t)l * NH + j;
    float v = f32m ? ((const float*)h0)[src] : bf2f(((const unsigned short*)h0)[src]);
    unsigned short hi = f2bf(v);
    unsigned short lo = f2bf(v - bf2f(hi));
    const size_t dst = ((size_t)(l * 2 + 1) * NB + b) * NH + j;   // parity 1
    act[dst] = ((unsigned int)hi << 16) | lo;
}

// ---------------- persistent pipeline kernel ----------------
__global__ __launch_bounds__(BLK, 2) void gru_persist(
    const void* __restrict__ x,
    const void* __restrict__ Wzi_, const void* __restrict__ Wzh_, const void* __restrict__ bzh_,
    const void* __restrict__ Wri_, const void* __restrict__ Wrh_, const void* __restrict__ brh_,
    const void* __restrict__ Wgi_, const void* __restrict__ Wgh_, const void* __restrict__ bgh_,
    void* __restrict__ dout,
    unsigned int* __restrict__ act,
    float* __restrict__ stfin,
    const int* __restrict__ flagp,
    unsigned int* __restrict__ gflags)
{
    extern __shared__ char lds[];
    float* clds = (float*)(lds + COFF);

    const int f32m = *flagp;
    const int tid  = threadIdx.x;
    const int wg   = blockIdx.x;
    const int lane = tid & 63;
    const int wid  = tid >> 6;          // 0..7
    const int Mtile = wid & 1;
    const int khalf = wid >> 1;         // 0..3 -> 256-col K slice
    const int n16  = lane & 15;
    const int q4   = lane >> 4;

    const int slot0 = wg * SLOTS;

    // ---- preload weights into LDS (bf16) ----
    {
        const void* Wmats[6] = {Wzi_, Wzh_, Wri_, Wrh_, Wgi_, Wgh_};
        if (f32m) {
            for (int idx = tid; idx < 72 * 256; idx += BLK) {
                const int r = idx >> 8, c4 = (idx & 255) * 4;
                const int slot = slot0 + r / 6, g = r % 6;
                const int layer = slot >> 10, j = slot & 1023;
                const float* src = (const float*)Wmats[g] + (size_t)layer * NH * NI + (size_t)j * NI + c4;
                float4 f = *(const float4*)src;
                unsigned short* dst = (unsigned short*)(lds + r * RPB + c4 * 2);
                dst[0] = f2bf(f.x); dst[1] = f2bf(f.y); dst[2] = f2bf(f.z); dst[3] = f2bf(f.w);
            }
        } else {
            for (int idx = tid; idx < 72 * 128; idx += BLK) {
                const int r = idx >> 7, c8 = (idx & 127) * 8;
                const int slot = slot0 + r / 6, g = r % 6;
                const int layer = slot >> 10, j = slot & 1023;
                const unsigned short* src = (const unsigned short*)Wmats[g] + (size_t)layer * NH * NI + (size_t)j * NI + c8;
                *(uint4*)(lds + r * RPB + c8 * 2) = *(const uint4*)src;
            }
        }
        unsigned int* z = (unsigned int*)(lds + ZROW * RPB);
        for (int c = tid; c < RPB / 4; c += BLK) z[c] = 0u;
    }

    // ---- epilogue thread state (tid < 384): biases + register h_prev ----
    int eci = 0, eb = 0, elg = 0, ej = 0;
    float ebz = 0.f, ebr = 0.f, ebg = 0.f, ehp = 0.f;
    if (tid < NB * SLOTS) {
        eci = tid % SLOTS; eb = tid / SLOTS;
        const int slot = slot0 + eci;
        elg = slot >> 10; ej = slot & 1023;
        const size_t bidx = (size_t)elg * NH + ej;
        if (f32m) {
            ebz = ((const float*)bzh_)[bidx];
            ebr = ((const float*)brh_)[bidx];
            ebg = ((const float*)bgh_)[bidx];
        } else {
            ebz = bf2f(((const unsigned short*)bzh_)[bidx]);
            ebr = bf2f(((const unsigned short*)brh_)[bidx]);
            ebg = bf2f(((const unsigned short*)bgh_)[bidx]);
        }
    }

    // ---- layer groups (slot range may straddle one layer boundary) ----
    const int lay0 = slot0 >> 10;
    const int lay1 = (slot0 + SLOTS - 1) >> 10;
    const int ngroups = (lay0 == lay1) ? 1 : 2;
    const int n0 = (ngroups == 1) ? SLOTS : (1024 - (slot0 & 1023));

    __syncthreads();

    for (int s = 0; s < NS + NL - 1; ++s) {
        for (int i = tid; i < 48 * CPITCH; i += BLK) clds[i] = 0.f;
        __syncthreads();

        floatx4 acc[3];
#pragma unroll
        for (int nt = 0; nt < 3; ++nt) acc[nt] = (floatx4){0.f, 0.f, 0.f, 0.f};

        for (int grp = 0; grp < ngroups; ++grp) {
            const int lg = (grp == 0) ? lay0 : lay1;
            const int t = s - lg;
            if (t < 0 || t >= NS) continue;
            const int ntLo = (grp == 0) ? 0 : ((4 * n0) >> 4);
            const int ntHi = (grp == 0) ? (ngroups == 1 ? 2 : ((4 * n0) >> 4) - 1) : 2;
            const int mb = Mtile * 16 + n16;

            for (int phase = 0; phase < 2; ++phase) {
                int brow[3];
#pragma unroll
                for (int nt = 0; nt < 3; ++nt) {
                    const int v = nt * 16 + n16;
                    const int ci = v >> 2, g = v & 3;
                    int r;
                    if (phase == 0) r = (g == 3) ? ZROW : ci * 6 + ((g == 2) ? 4 : g * 2);
                    else            r = (g == 2) ? ZROW : ci * 6 + ((g == 3) ? 5 : g * 2 + 1);
                    brow[nt] = r;
                }

                const bool isx = (phase == 0 && lg == 0);
                const bool dolo = isx ? (f32m != 0) : true;

                // hoist all A-frags for this phase into registers
                short8 AH[8], AL[8];
                if (isx) {
                    if (f32m) {
                        const float* xb = (const float*)x + ((size_t)mb * NS + t) * NI + khalf * 256 + q4 * 8;
#pragma unroll
                        for (int ks = 0; ks < 8; ++ks) {
                            float f[8];
                            load8f(xb + ks * 32, f);
#pragma unroll
                            for (int e = 0; e < 8; ++e) {
                                unsigned short h = f2bf(f[e]);
                                AH[ks][e] = (short)h;
                                AL[ks][e] = (short)f2bf(f[e] - bf2f(h));
                            }
                        }
                    } else {
                        const unsigned short* xb = (const unsigned short*)x + ((size_t)mb * NS + t) * NI + khalf * 256 + q4 * 8;
#pragma unroll
                        for (int ks = 0; ks < 8; ++ks)
                            AH[ks] = *(const short8*)(xb + ks * 32);
                    }
                } else {
                    const int src_l = (phase == 0) ? lg - 1 : lg;
                    const int src_p = (phase == 0) ? (t & 1) : ((t - 1) & 1);
                    const size_t ab = ((size_t)(src_l * 2 + src_p) * NB + mb) * NH + khalf * 256 + q4 * 8;
                    const unsigned long long* ap = (const unsigned long long*)(act + ab);
                    // issue all 32 L3-coherent loads first, then unpack
                    unsigned long long qq[8][4];
#pragma unroll
                    for (int ks = 0; ks < 8; ++ks)
#pragma unroll
                        for (int i = 0; i < 4; ++i)
                            qq[ks][i] = __hip_atomic_load(ap + (size_t)ks * 16 + i,
                                                          __ATOMIC_RELAXED, __HIP_MEMORY_SCOPE_AGENT);
#pragma unroll
                    for (int ks = 0; ks < 8; ++ks) {
#pragma unroll
                        for (int i = 0; i < 4; ++i) {
                            const unsigned int c0 = (unsigned int)qq[ks][i];
                            const unsigned int c1 = (unsigned int)(qq[ks][i] >> 32);
                            AH[ks][2*i]   = (short)(c0 >> 16);
                            AL[ks][2*i]   = (short)(c0 & 0xffffu);
                            AH[ks][2*i+1] = (short)(c1 >> 16);
                            AL[ks][2*i+1] = (short)(c1 & 0xffffu);
                        }
                    }
                }

#pragma unroll
                for (int ks = 0; ks < 8; ++ks) {
                    const int k0 = khalf * 256 + ks * 32;
#pragma unroll
                    for (int nt = 0; nt < 3; ++nt) {
                        if (nt < ntLo || nt > ntHi) continue;
                        const short8 bf = *(const short8*)(lds + brow[nt] * RPB + k0 * 2 + q4 * 16);
                        acc[nt] = __builtin_amdgcn_mfma_f32_16x16x32_bf16(AH[ks], bf, acc[nt], 0, 0, 0);
                        if (dolo)
                            acc[nt] = __builtin_amdgcn_mfma_f32_16x16x32_bf16(AL[ks], bf, acc[nt], 0, 0, 0);
                    }
                }
            }
        }

        // dump accumulators (C/D: col=lane&15, row=q4*4+reg)
        {
            const int mbase = Mtile * 16 + q4 * 4;
#pragma unroll
            for (int nt = 0; nt < 3; ++nt) {
                const int vcol = nt * 16 + n16;
#pragma unroll
                for (int r = 0; r < 4; ++r)
                    atomicAdd(&clds[vcol * CPITCH + mbase + r], acc[nt][r]);
            }
        }
        __syncthreads();

        // epilogue: one thread per (col, batch)
        if (tid < NB * SLOTS) {
            const int t = s - elg;
            if (t >= 0 && t < NS) {
                const float zp = clds[(eci * 4 + 0) * CPITCH + eb];
                const float rp = clds[(eci * 4 + 1) * CPITCH + eb];
                const float gi = clds[(eci * 4 + 2) * CPITCH + eb];
                const float gh = clds[(eci * 4 + 3) * CPITCH + eb];
                float hp;
                if (t == 0) {
                    const size_t hoff = ((size_t)(elg * 2 + 1) * NB + eb) * NH + ej;
                    const unsigned int pv = __hip_atomic_load(&act[hoff],
                                                              __ATOMIC_RELAXED, __HIP_MEMORY_SCOPE_AGENT);
                    hp = bf2f((unsigned short)(pv >> 16)) + bf2f((unsigned short)(pv & 0xffffu));
                } else {
                    hp = ehp;
                }
                const float z = 1.f / (1.f + expf(-(zp + ebz)));
                const float r = 1.f / (1.f + expf(-(rp + ebr)));
                const float g = tanhf(gi + r * (gh + ebg));
                const float hn = z * hp + (1.f - z) * g;
                ehp = hn;
                const unsigned short hi = f2bf(hn);
                const unsigned short lo = f2bf(hn - bf2f(hi));
                const size_t woff = ((size_t)(elg * 2 + (t & 1)) * NB + eb) * NH + ej;
                __hip_atomic_store(&act[woff], ((unsigned int)hi << 16) | lo,
                                   __ATOMIC_RELAXED, __HIP_MEMORY_SCOPE_AGENT);
                if (elg == 2) {
                    const size_t o = ((size_t)eb * NS + t) * NO + ej;
                    if (f32m) ((float*)dout)[o] = hn;
                    else      ((unsigned short*)dout)[o] = f2bf(hn);
                }
                if (t == NS - 1)
                    stfin[((size_t)elg * NB + eb) * NH + ej] = hn;
            }
        }

        // ---- 2-hop master barrier, zero cache-maintenance ops ----
        // act stores are sc1: __syncthreads' vmcnt(0) drain makes them
        // L3-visible before tid0's flag store. RELAXED publish -> no wbl2.
        __syncthreads();
        if (tid == 0)
            __hip_atomic_store(&gflags[wg * 32], (unsigned int)(s + 1),
                               __ATOMIC_RELAXED, __HIP_MEMORY_SCOPE_AGENT);
        if (wg == 0) {
            // master: 4 waves poll all 256 per-WG flags (1 lane : 1 flag)
            if (tid < WGN) {
                while (__hip_atomic_load(&gflags[tid * 32], __ATOMIC_RELAXED,
                                         __HIP_MEMORY_SCOPE_AGENT) <= (unsigned int)s)
                    __builtin_amdgcn_s_sleep(2);
            }
            __syncthreads();   // all 256 arrivals observed
            if (tid == 0)
                __hip_atomic_store(&gflags[WGN * 32], (unsigned int)(s + 1),
                                   __ATOMIC_RELAXED, __HIP_MEMORY_SCOPE_AGENT);
        } else {
            // everyone else: single lane polls the generation line
            if (tid == 0) {
                while (__hip_atomic_load(&gflags[WGN * 32], __ATOMIC_RELAXED,
                                         __HIP_MEMORY_SCOPE_AGENT) <= (unsigned int)s)
                    __builtin_amdgcn_s_sleep(2);
            }
            __syncthreads();
        }
    }
}

// ---------------- fallback kernels (round-2, proven) ----------------
__global__ void init_kernel(const void* __restrict__ h0, float* __restrict__ st,
                            const int* __restrict__ flagp) {
    const int f32m = *flagp;
    const int idx = blockIdx.x * 256 + threadIdx.x;
    if (idx >= NL * NB * NH) return;
    const int l = idx >> 15;
    const int b = (idx >> 10) & 31;
    const int j = idx & 1023;
    const size_t src = (size_t)b * NL * NH + (size_t)l * NH + j;
    st[idx] = f32m ? ((const float*)h0)[src] : bf2f(((const unsigned short*)h0)[src]);
}

__global__ __launch_bounds__(256) void gru_layer(
    const void*  __restrict__ x,
    const float* __restrict__ inp,
    const float* __restrict__ hprev,
    float*       __restrict__ hnew,
    void*        __restrict__ h2out,
    const void* __restrict__ Wzi_, const void* __restrict__ Wzh_, const void* __restrict__ bzh_,
    const void* __restrict__ Wri_, const void* __restrict__ Wrh_, const void* __restrict__ brh_,
    const void* __restrict__ Wgi_, const void* __restrict__ Wgh_, const void* __restrict__ bgh_,
    const int* __restrict__ flagp, int tl, int isX)
{
    __shared__ float s_in[NB][129];
    __shared__ float s_h [NB][129];
    __shared__ float s_red[256][6];

    const int f32m = *flagp;
    const int t = tl & 0xFFFF;
    const int l = tl >> 16;
    const int tid = threadIdx.x;
    const int b   = tid & 31;
    const int jl  = (tid >> 5) & 1;
    const int ks  = tid >> 6;
    const int j   = blockIdx.x * 2 + jl;

    const size_t wIl = (size_t)l * NH * NI + (size_t)j * NI;
    const size_t bl  = (size_t)l * NH + j;

    float azi = 0.f, azh = 0.f, ari = 0.f, arh = 0.f, agi = 0.f, agh = 0.f;

    for (int kc = 0; kc < 8; ++kc) {
        const int k0 = kc * 128;
        __syncthreads();
        for (int idx = tid; idx < NB * 128; idx += 256) {
            const int r = idx >> 7, c = idx & 127;
            float vi;
            if (isX) {
                const size_t xo = (size_t)r * NS * NI + (size_t)t * NI + (k0 + c);
                vi = f32m ? ((const float*)x)[xo] : bf2f(((const unsigned short*)x)[xo]);
            } else {
                vi = inp[r * NH + k0 + c];
            }
            s_in[r][c] = vi;
            s_h [r][c] = hprev[r * NH + k0 + c];
        }
        __syncthreads();

        const int cbase = ks * 32;
#pragma unroll
        for (int q8 = 0; q8 < 4; ++q8) {
            const int c = cbase + q8 * 8;
            const int k = k0 + c;
            float wz[8], wr[8], wg[8], vz[8], vr[8], vg[8];
            if (f32m) {
                load8f((const float*)Wzi_ + wIl + k, wz);
                load8f((const float*)Wri_ + wIl + k, wr);
                load8f((const float*)Wgi_ + wIl + k, wg);
                load8f((const float*)Wzh_ + wIl + k, vz);
                load8f((const float*)Wrh_ + wIl + k, vr);
                load8f((const float*)Wgh_ + wIl + k, vg);
            } else {
                load8h((const unsigned short*)Wzi_ + wIl + k, wz);
                load8h((const unsigned short*)Wri_ + wIl + k, wr);
                load8h((const unsigned short*)Wgi_ + wIl + k, wg);
                load8h((const unsigned short*)Wzh_ + wIl + k, vz);
                load8h((const unsigned short*)Wrh_ + wIl + k, vr);
                load8h((const unsigned short*)Wgh_ + wIl + k, vg);
            }
            float ai[8], ah[8];
#pragma unroll
            for (int q = 0; q < 8; ++q) { ai[q] = s_in[b][c + q]; ah[q] = s_h[b][c + q]; }
#pragma unroll
            for (int q = 0; q < 8; ++q) {
                azi = fmaf(wz[q], ai[q], azi);
                ari = fmaf(wr[q], ai[q], ari);
                agi = fmaf(wg[q], ai[q], agi);
                azh = fmaf(vz[q], ah[q], azh);
                arh = fmaf(vr[q], ah[q], arh);
                agh = fmaf(vg[q], ah[q], agh);
            }
        }
    }

    s_red[tid][0] = azi; s_red[tid][1] = azh; s_red[tid][2] = ari;
    s_red[tid][3] = arh; s_red[tid][4] = agi; s_red[tid][5] = agh;
    __syncthreads();

    if (ks == 0) {
#pragma unroll
        for (int w = 1; w < 4; ++w) {
            azi += s_red[tid + 64*w][0]; azh += s_red[tid + 64*w][1];
            ari += s_red[tid + 64*w][2]; arh += s_red[tid + 64*w][3];
            agi += s_red[tid + 64*w][4]; agh += s_red[tid + 64*w][5];
        }
        const float bz = f32m ? ((const float*)bzh_)[bl] : bf2f(((const unsigned short*)bzh_)[bl]);
        const float br = f32m ? ((const float*)brh_)[bl] : bf2f(((const unsigned short*)brh_)[bl]);
        const float bg = f32m ? ((const float*)bgh_)[bl] : bf2f(((const unsigned short*)bgh_)[bl]);
        const float z = 1.f / (1.f + expf(-(azi + azh + bz)));
        const float r = 1.f / (1.f + expf(-(ari + arh + br)));
        const float g = tanhf(agi + r * (agh + bg));
        const float hp = hprev[b * NH + j];
        const float hn = z * hp + (1.f - z) * g;
        hnew[b * NH + j] = hn;
        if (h2out) {
            const size_t off = (size_t)b * NS * NO + (size_t)t * NO + j;
            if (f32m) ((float*)h2out)[off] = hn;
            else      ((unsigned short*)h2out)[off] = f2bf(hn);
        }
    }
}

__global__ __launch_bounds__(256) void out_gemm(
    void* __restrict__ out, const void* __restrict__ Wout, const void* __restrict__ bout,
    const int* __restrict__ flagp)
{
    __shared__ float s_a[8][1024];
    const int f32m = *flagp;
    const int tid = threadIdx.x;
    const size_t row0 = (size_t)blockIdx.x * 8;

    for (int idx = tid; idx < 8 * 1024; idx += 256) {
        const int r = idx >> 10, c = idx & 1023;
        const size_t off = (row0 + r) * NO + c;
        s_a[r][c] = f32m ? ((const float*)out)[off] : bf2f(((const unsigned short*)out)[off]);
    }
    __syncthreads();

    float acc[4][8];
#pragma unroll
    for (int m = 0; m < 4; ++m)
#pragma unroll
        for (int r = 0; r < 8; ++r) acc[m][r] = 0.f;

    for (int k8 = 0; k8 < 128; ++k8) {
        const int k = k8 * 8;
        float wf[4][8];
#pragma unroll
        for (int m = 0; m < 4; ++m) {
            const size_t wo = (size_t)(tid + 256*m) * NH + k;
            if (f32m) load8f((const float*)Wout + wo, wf[m]);
            else      load8h((const unsigned short*)Wout + wo, wf[m]);
        }
#pragma unroll
        for (int r = 0; r < 8; ++r) {
            float a[8];
#pragma unroll
            for (int q = 0; q < 8; ++q) a[q] = s_a[r][k + q];
#pragma unroll
            for (int m = 0; m < 4; ++m)
#pragma unroll
                for (int q = 0; q < 8; ++q)
                    acc[m][r] = fmaf(wf[m][q], a[q], acc[m][r]);
        }
    }

#pragma unroll
    for (int m = 0; m < 4; ++m) {
        const int jj = tid + 256*m;
        const float bj = f32m ? ((const float*)bout)[jj] : bf2f(((const unsigned short*)bout)[jj]);
#pragma unroll
        for (int r = 0; r < 8; ++r) {
            const size_t off = (row0 + r) * NO + jj;
            const float v = acc[m][r] + bj;
            if (f32m) ((float*)out)[off] = v;
            else      ((unsigned short*)out)[off] = f2bf(v);
        }
    }
}

__global__ void tail_kernel(const float* __restrict__ st, void* __restrict__ out,
                            const int* __restrict__ flagp)
{
    const int f32m = *flagp;
    const int idx = blockIdx.x * 256 + threadIdx.x;
    if (idx >= NL * NB * NH) return;
    const int l = idx >> 15;
    const int b = (idx >> 10) & 31;
    const int j = idx & 1023;
    const size_t dst = (size_t)NB * NS * NO + (size_t)b * NL * NH + (size_t)l * NH + j;
    if (f32m) ((float*)out)[dst] = st[idx];
    else      ((unsigned short*)out)[dst] = f2bf(st[idx]);
}

// ---------------- host ----------------
extern "C" void kernel_launch(void* const* d_in, const int* in_sizes, int n_in,
                              void* d_out, int out_size, void* d_ws, size_t ws_size,
                              hipStream_t stream)
{
    const void* x    = d_in[0];
    const void* h0   = d_in[1];
    const void* Wzi  = d_in[2];
    const void* Wzh  = d_in[3];
    const void* bzh  = d_in[4];
    const void* Wri  = d_in[5];
    const void* Wrh  = d_in[6];
    const void* brh  = d_in[7];
    const void* Wgi  = d_in[8];
    const void* Wgh  = d_in[9];
    const void* bgh  = d_in[10];
    const void* Wout = d_in[11];
    const void* bout = d_in[12];

    // ws layout
    char* w = (char*)d_ws;
    float* st            = (float*)w;                       // [2][3][32][1024] f32
    int*   flag          = (int*)(w + 786432);
    unsigned int* act    = (unsigned int*)(w + 786464);     // [3][2][32][1024] packed hi|lo, ends 1,572,896
    unsigned int* gflags = (unsigned int*)(w + 1572992);    // 256 flag lines + 1 gen line, ends 1,605,888
    auto stp = [&](int p, int l) { return st + ((size_t)(p * NL + l)) * NB * NH; };

    detect_kernel<<<1, 256, 0, stream>>>((const unsigned int*)x, flag);
    init_act<<<(NL*NB*NH + 255)/256, 256, 0, stream>>>(h0, act, gflags, flag);

    (void)hipFuncSetAttribute((const void*)gru_persist,
                              hipFuncAttributeMaxDynamicSharedMemorySize, LDSB);
    (void)hipGetLastError();   // clear
    gru_persist<<<WGN, BLK, LDSB, stream>>>(
        x, Wzi, Wzh, bzh, Wri, Wrh, brh, Wgi, Wgh, bgh,
        d_out, act, st /* final h */, flag, gflags);
    hipError_t perr = hipGetLastError();

    if (perr != hipSuccess) {
        init_kernel<<<(NL*NB*NH + 255)/256, 256, 0, stream>>>(h0, st, flag);
        for (int t = 0; t < NS; ++t) {
            const int pr = t & 1, pw = 1 - pr;
            for (int l = 0; l < NL; ++l) {
                gru_layer<<<512, 256, 0, stream>>>(
                    x,
                    l == 0 ? st : stp(pw, l - 1),
                    stp(pr, l),
                    stp(pw, l),
                    l == 2 ? d_out : (void*)nullptr,
                    Wzi, Wzh, bzh, Wri, Wrh, brh, Wgi, Wgh, bgh,
                    flag, t | (l << 16), l == 0 ? 1 : 0);
            }
        }
    }

    out_gemm<<<NB * NS / 8, 256, 0, stream>>>(d_out, Wout, bout, flag);
    tail_kernel<<<(NL*NB*NH + 255)/256, 256, 0, stream>>>(st, d_out, flag);
}

// Round 3
// 14248.051 us; speedup vs baseline: 2.6790x; 1.3332x over previous
//
#include <hip/hip_runtime.h>
#include <hip/hip_bf16.h>

// MultilayerGRU: B=32 S=512 I=H=O=1024 L=3.
// Round 7: cache the act broadcast.
//  - act A-operand loads were agent-scope sc1 (bypass L1/L2, served by
//    fabric/L3): 64 MB/step of uncached broadcast ~= the whole 34us step at
//    ~1 TB/s/XCD bypass fill rate. Now PLAIN cached loads (dwordx4).
//  - coherence restored by ONE acquire fence (buffer_inv sc1: invalidates
//    this CU's L1 + this XCD's L2) per WG per step, issued by tid0 right
//    after it observes the barrier generation, before __syncthreads.
//    Writers still use relaxed sc1 STORES (write-through to L3) so L2 never
//    holds dirty act lines -> no wbl2 anywhere. After any inv-since-barrier,
//    every act line in L2 is fresh by construction; the full barrier already
//    separates step-s reads from step-s+1 writes (parity double-buffer).
//  - 256 invs/step total (vs round-0's ~1e5 storm).

#define NB 32
#define NS 512
#define NI 1024
#define NH 1024
#define NL 3
#define NO 1024

#define WGN 256
#define BLK 512
#define SLOTS 12
#define RPB 2096                 // weight row pitch bytes; 524 dwords == 12 mod 32 -> 2-way max (free)
#define ZROW 72                  // zero-row index
#define COFF (73 * RPB)          // 153,008
#define CPITCH 33                // 33 dwords == 1 mod 32 -> conflict-free
#define LDSB (COFF + 48 * CPITCH * 4)   // 159,344 <= 163,840

using short8 = __attribute__((ext_vector_type(8))) short;
using floatx4 = __attribute__((ext_vector_type(4))) float;

static __device__ __forceinline__ float bf2f(unsigned short u) {
    union { unsigned int i; float f; } v;
    v.i = ((unsigned int)u) << 16;
    return v.f;
}

static __device__ __forceinline__ unsigned short f2bf(float f) {
    __hip_bfloat16 h = __float2bfloat16(f);   // RNE
    union { __hip_bfloat16 h; unsigned short u; } v;
    v.h = h;
    return v.u;
}

static __device__ __forceinline__ void load8h(const unsigned short* p, float w[8]) {
    uint4 q = *(const uint4*)p;
    unsigned int u[4] = {q.x, q.y, q.z, q.w};
#pragma unroll
    for (int i = 0; i < 4; ++i) {
        w[2*i]   = __uint_as_float(u[i] << 16);
        w[2*i+1] = __uint_as_float(u[i] & 0xffff0000u);
    }
}

static __device__ __forceinline__ void load8f(const float* p, float w[8]) {
    float4 a = *(const float4*)p;
    float4 b = *(const float4*)(p + 4);
    w[0]=a.x; w[1]=a.y; w[2]=a.z; w[3]=a.w;
    w[4]=b.x; w[5]=b.y; w[6]=b.z; w[7]=b.w;
}

// ---------------- dtype detection ----------------
__global__ void detect_kernel(const unsigned int* __restrict__ xw, int* __restrict__ flag) {
    __shared__ int cnt[256];
    int c = 0;
    for (int i = threadIdx.x; i < 1024; i += 256) {
        unsigned int e = (xw[i] >> 7) & 0xFFu;
        if (e >= 0x78u && e <= 0x84u) c++;
    }
    cnt[threadIdx.x] = c;
    __syncthreads();
    if (threadIdx.x == 0) {
        int s = 0;
        for (int i = 0; i < 256; ++i) s += cnt[i];
        *flag = (s < 512) ? 1 : 0;
    }
}

// ---------------- init: h0 -> act parity-1 packed (hi<<16|lo); zero flags+gen ----
__global__ void init_act(const void* __restrict__ h0,
                         unsigned int* __restrict__ act,
                         unsigned int* __restrict__ gflags,
                         const int* __restrict__ flagp) {
    const int f32m = *flagp;
    const int idx = blockIdx.x * 256 + threadIdx.x;  // l*32768 + b*1024 + j
    if (idx < WGN * 32 + 32) gflags[idx] = 0u;       // 256 flag lines + gen line
    if (idx >= NL * NB * NH) return;
    const int l = idx >> 15;
    const int b = (idx >> 10) & 31;
    const int j = idx & 1023;
    const size_t src = (size_t)b * NL * NH + (size_t)l * NH + j;
    float v = f32m ? ((const float*)h0)[src] : bf2f(((const unsigned short*)h0)[src]);
    unsigned short hi = f2bf(v);
    unsigned short lo = f2bf(v - bf2f(hi));
    const size_t dst = ((size_t)(l * 2 + 1) * NB + b) * NH + j;   // parity 1
    act[dst] = ((unsigned int)hi << 16) | lo;
}

// ---------------- persistent pipeline kernel ----------------
__global__ __launch_bounds__(BLK, 2) void gru_persist(
    const void* __restrict__ x,
    const void* __restrict__ Wzi_, const void* __restrict__ Wzh_, const void* __restrict__ bzh_,
    const void* __restrict__ Wri_, const void* __restrict__ Wrh_, const void* __restrict__ brh_,
    const void* __restrict__ Wgi_, const void* __restrict__ Wgh_, const void* __restrict__ bgh_,
    void* __restrict__ dout,
    unsigned int* __restrict__ act,
    float* __restrict__ stfin,
    const int* __restrict__ flagp,
    unsigned int* __restrict__ gflags)
{
    extern __shared__ char lds[];
    float* clds = (float*)(lds + COFF);

    const int f32m = *flagp;
    const int tid  = threadIdx.x;
    const int wg   = blockIdx.x;
    const int lane = tid & 63;
    const int wid  = tid >> 6;          // 0..7
    const int Mtile = wid & 1;
    const int khalf = wid >> 1;         // 0..3 -> 256-col K slice
    const int n16  = lane & 15;
    const int q4   = lane >> 4;

    const int slot0 = wg * SLOTS;

    // ---- preload weights into LDS (bf16) ----
    {
        const void* Wmats[6] = {Wzi_, Wzh_, Wri_, Wrh_, Wgi_, Wgh_};
        if (f32m) {
            for (int idx = tid; idx < 72 * 256; idx += BLK) {
                const int r = idx >> 8, c4 = (idx & 255) * 4;
                const int slot = slot0 + r / 6, g = r % 6;
                const int layer = slot >> 10, j = slot & 1023;
                const float* src = (const float*)Wmats[g] + (size_t)layer * NH * NI + (size_t)j * NI + c4;
                float4 f = *(const float4*)src;
                unsigned short* dst = (unsigned short*)(lds + r * RPB + c4 * 2);
                dst[0] = f2bf(f.x); dst[1] = f2bf(f.y); dst[2] = f2bf(f.z); dst[3] = f2bf(f.w);
            }
        } else {
            for (int idx = tid; idx < 72 * 128; idx += BLK) {
                const int r = idx >> 7, c8 = (idx & 127) * 8;
                const int slot = slot0 + r / 6, g = r % 6;
                const int layer = slot >> 10, j = slot & 1023;
                const unsigned short* src = (const unsigned short*)Wmats[g] + (size_t)layer * NH * NI + (size_t)j * NI + c8;
                *(uint4*)(lds + r * RPB + c8 * 2) = *(const uint4*)src;
            }
        }
        unsigned int* z = (unsigned int*)(lds + ZROW * RPB);
        for (int c = tid; c < RPB / 4; c += BLK) z[c] = 0u;
    }

    // ---- epilogue thread state (tid < 384): biases + register h_prev ----
    int eci = 0, eb = 0, elg = 0, ej = 0;
    float ebz = 0.f, ebr = 0.f, ebg = 0.f, ehp = 0.f;
    if (tid < NB * SLOTS) {
        eci = tid % SLOTS; eb = tid / SLOTS;
        const int slot = slot0 + eci;
        elg = slot >> 10; ej = slot & 1023;
        const size_t bidx = (size_t)elg * NH + ej;
        if (f32m) {
            ebz = ((const float*)bzh_)[bidx];
            ebr = ((const float*)brh_)[bidx];
            ebg = ((const float*)bgh_)[bidx];
        } else {
            ebz = bf2f(((const unsigned short*)bzh_)[bidx]);
            ebr = bf2f(((const unsigned short*)brh_)[bidx]);
            ebg = bf2f(((const unsigned short*)bgh_)[bidx]);
        }
    }

    // ---- layer groups (slot range may straddle one layer boundary) ----
    const int lay0 = slot0 >> 10;
    const int lay1 = (slot0 + SLOTS - 1) >> 10;
    const int ngroups = (lay0 == lay1) ? 1 : 2;
    const int n0 = (ngroups == 1) ? SLOTS : (1024 - (slot0 & 1023));

    __syncthreads();

    for (int s = 0; s < NS + NL - 1; ++s) {
        for (int i = tid; i < 48 * CPITCH; i += BLK) clds[i] = 0.f;
        __syncthreads();

        floatx4 acc[3];
#pragma unroll
        for (int nt = 0; nt < 3; ++nt) acc[nt] = (floatx4){0.f, 0.f, 0.f, 0.f};

        for (int grp = 0; grp < ngroups; ++grp) {
            const int lg = (grp == 0) ? lay0 : lay1;
            const int t = s - lg;
            if (t < 0 || t >= NS) continue;
            const int ntLo = (grp == 0) ? 0 : ((4 * n0) >> 4);
            const int ntHi = (grp == 0) ? (ngroups == 1 ? 2 : ((4 * n0) >> 4) - 1) : 2;
            const int mb = Mtile * 16 + n16;

            for (int phase = 0; phase < 2; ++phase) {
                int brow[3];
#pragma unroll
                for (int nt = 0; nt < 3; ++nt) {
                    const int v = nt * 16 + n16;
                    const int ci = v >> 2, g = v & 3;
                    int r;
                    if (phase == 0) r = (g == 3) ? ZROW : ci * 6 + ((g == 2) ? 4 : g * 2);
                    else            r = (g == 2) ? ZROW : ci * 6 + ((g == 3) ? 5 : g * 2 + 1);
                    brow[nt] = r;
                }

                const bool isx = (phase == 0 && lg == 0);
                const bool dolo = isx ? (f32m != 0) : true;

                // hoist all A-frags for this phase into registers
                short8 AH[8], AL[8];
                if (isx) {
                    if (f32m) {
                        const float* xb = (const float*)x + ((size_t)mb * NS + t) * NI + khalf * 256 + q4 * 8;
#pragma unroll
                        for (int ks = 0; ks < 8; ++ks) {
                            float f[8];
                            load8f(xb + ks * 32, f);
#pragma unroll
                            for (int e = 0; e < 8; ++e) {
                                unsigned short h = f2bf(f[e]);
                                AH[ks][e] = (short)h;
                                AL[ks][e] = (short)f2bf(f[e] - bf2f(h));
                            }
                        }
                    } else {
                        const unsigned short* xb = (const unsigned short*)x + ((size_t)mb * NS + t) * NI + khalf * 256 + q4 * 8;
#pragma unroll
                        for (int ks = 0; ks < 8; ++ks)
                            AH[ks] = *(const short8*)(xb + ks * 32);
                    }
                } else {
                    const int src_l = (phase == 0) ? lg - 1 : lg;
                    const int src_p = (phase == 0) ? (t & 1) : ((t - 1) & 1);
                    const size_t ab = ((size_t)(src_l * 2 + src_p) * NB + mb) * NH + khalf * 256 + q4 * 8;
                    // PLAIN cached loads (L1/L2); coherence via the per-step
                    // acquire-inv issued after the barrier below.
                    const uint4* ap = (const uint4*)(act + ab);
                    uint4 qq[16];
#pragma unroll
                    for (int ks = 0; ks < 8; ++ks) {
                        qq[2*ks]   = ap[ks * 8];       // u32 elems ks*32 + 0..3
                        qq[2*ks+1] = ap[ks * 8 + 1];   // u32 elems ks*32 + 4..7
                    }
#pragma unroll
                    for (int ks = 0; ks < 8; ++ks) {
                        unsigned int c[8] = {qq[2*ks].x, qq[2*ks].y, qq[2*ks].z, qq[2*ks].w,
                                             qq[2*ks+1].x, qq[2*ks+1].y, qq[2*ks+1].z, qq[2*ks+1].w};
#pragma unroll
                        for (int e = 0; e < 8; ++e) {
                            AH[ks][e] = (short)(c[e] >> 16);
                            AL[ks][e] = (short)(c[e] & 0xffffu);
                        }
                    }
                }

#pragma unroll
                for (int ks = 0; ks < 8; ++ks) {
                    const int k0 = khalf * 256 + ks * 32;
#pragma unroll
                    for (int nt = 0; nt < 3; ++nt) {
                        if (nt < ntLo || nt > ntHi) continue;
                        const short8 bf = *(const short8*)(lds + brow[nt] * RPB + k0 * 2 + q4 * 16);
                        acc[nt] = __builtin_amdgcn_mfma_f32_16x16x32_bf16(AH[ks], bf, acc[nt], 0, 0, 0);
                        if (dolo)
                            acc[nt] = __builtin_amdgcn_mfma_f32_16x16x32_bf16(AL[ks], bf, acc[nt], 0, 0, 0);
                    }
                }
            }
        }

        // dump accumulators (C/D: col=lane&15, row=q4*4+reg)
        {
            const int mbase = Mtile * 16 + q4 * 4;
#pragma unroll
            for (int nt = 0; nt < 3; ++nt) {
                const int vcol = nt * 16 + n16;
#pragma unroll
                for (int r = 0; r < 4; ++r)
                    atomicAdd(&clds[vcol * CPITCH + mbase + r], acc[nt][r]);
            }
        }
        __syncthreads();

        // epilogue: one thread per (col, batch)
        if (tid < NB * SLOTS) {
            const int t = s - elg;
            if (t >= 0 && t < NS) {
                const float zp = clds[(eci * 4 + 0) * CPITCH + eb];
                const float rp = clds[(eci * 4 + 1) * CPITCH + eb];
                const float gi = clds[(eci * 4 + 2) * CPITCH + eb];
                const float gh = clds[(eci * 4 + 3) * CPITCH + eb];
                float hp;
                if (t == 0) {
                    const size_t hoff = ((size_t)(elg * 2 + 1) * NB + eb) * NH + ej;
                    const unsigned int pv = act[hoff];   // init_act wrote it (pre-kernel), cached load fine
                    hp = bf2f((unsigned short)(pv >> 16)) + bf2f((unsigned short)(pv & 0xffffu));
                } else {
                    hp = ehp;
                }
                const float z = 1.f / (1.f + expf(-(zp + ebz)));
                const float r = 1.f / (1.f + expf(-(rp + ebr)));
                const float g = tanhf(gi + r * (gh + ebg));
                const float hn = z * hp + (1.f - z) * g;
                ehp = hn;
                const unsigned short hi = f2bf(hn);
                const unsigned short lo = f2bf(hn - bf2f(hi));
                const size_t woff = ((size_t)(elg * 2 + (t & 1)) * NB + eb) * NH + ej;
                // sc1 write-through store: lands in L3, never dirty in L2
                __hip_atomic_store(&act[woff], ((unsigned int)hi << 16) | lo,
                                   __ATOMIC_RELAXED, __HIP_MEMORY_SCOPE_AGENT);
                if (elg == 2) {
                    const size_t o = ((size_t)eb * NS + t) * NO + ej;
                    if (f32m) ((float*)dout)[o] = hn;
                    else      ((unsigned short*)dout)[o] = f2bf(hn);
                }
                if (t == NS - 1)
                    stfin[((size_t)elg * NB + eb) * NH + ej] = hn;
            }
        }

        // ---- 2-hop master barrier + per-WG acquire-inv ----
        // act stores are sc1: __syncthreads' vmcnt(0) drain makes them
        // L3-visible before tid0's flag store (relaxed -> no wbl2).
        // After observing the generation advance, tid0 issues ONE acquire
        // fence (buffer_inv sc1: invalidates this CU's L1 + this XCD's L2);
        // the trailing __syncthreads orders every wave's next-step cached
        // loads after the completed inv.
        __syncthreads();
        if (tid == 0)
            __hip_atomic_store(&gflags[wg * 32], (unsigned int)(s + 1),
                               __ATOMIC_RELAXED, __HIP_MEMORY_SCOPE_AGENT);
        if (wg == 0) {
            // master: 4 waves poll all 256 per-WG flags (1 lane : 1 flag)
            if (tid < WGN) {
                while (__hip_atomic_load(&gflags[tid * 32], __ATOMIC_RELAXED,
                                         __HIP_MEMORY_SCOPE_AGENT) <= (unsigned int)s)
                    __builtin_amdgcn_s_sleep(2);
            }
            __syncthreads();   // all 256 arrivals observed
            if (tid == 0) {
                __hip_atomic_store(&gflags[WGN * 32], (unsigned int)(s + 1),
                                   __ATOMIC_RELAXED, __HIP_MEMORY_SCOPE_AGENT);
                __builtin_amdgcn_fence(__ATOMIC_ACQUIRE, "agent");   // inv L1+L2
            }
            __syncthreads();
        } else {
            // everyone else: single lane polls the generation line
            if (tid == 0) {
                while (__hip_atomic_load(&gflags[WGN * 32], __ATOMIC_RELAXED,
                                         __HIP_MEMORY_SCOPE_AGENT) <= (unsigned int)s)
                    __builtin_amdgcn_s_sleep(2);
                __builtin_amdgcn_fence(__ATOMIC_ACQUIRE, "agent");   // inv L1+L2
            }
            __syncthreads();
        }
    }
}

// ---------------- fallback kernels (round-2, proven) ----------------
__global__ void init_kernel(const void* __restrict__ h0, float* __restrict__ st,
                            const int* __restrict__ flagp) {
    const int f32m = *flagp;
    const int idx = blockIdx.x * 256 + threadIdx.x;
    if (idx >= NL * NB * NH) return;
    const int l = idx >> 15;
    const int b = (idx >> 10) & 31;
    const int j = idx & 1023;
    const size_t src = (size_t)b * NL * NH + (size_t)l * NH + j;
    st[idx] = f32m ? ((const float*)h0)[src] : bf2f(((const unsigned short*)h0)[src]);
}

__global__ __launch_bounds__(256) void gru_layer(
    const void*  __restrict__ x,
    const float* __restrict__ inp,
    const float* __restrict__ hprev,
    float*       __restrict__ hnew,
    void*        __restrict__ h2out,
    const void* __restrict__ Wzi_, const void* __restrict__ Wzh_, const void* __restrict__ bzh_,
    const void* __restrict__ Wri_, const void* __restrict__ Wrh_, const void* __restrict__ brh_,
    const void* __restrict__ Wgi_, const void* __restrict__ Wgh_, const void* __restrict__ bgh_,
    const int* __restrict__ flagp, int tl, int isX)
{
    __shared__ float s_in[NB][129];
    __shared__ float s_h [NB][129];
    __shared__ float s_red[256][6];

    const int f32m = *flagp;
    const int t = tl & 0xFFFF;
    const int l = tl >> 16;
    const int tid = threadIdx.x;
    const int b   = tid & 31;
    const int jl  = (tid >> 5) & 1;
    const int ks  = tid >> 6;
    const int j   = blockIdx.x * 2 + jl;

    const size_t wIl = (size_t)l * NH * NI + (size_t)j * NI;
    const size_t bl  = (size_t)l * NH + j;

    float azi = 0.f, azh = 0.f, ari = 0.f, arh = 0.f, agi = 0.f, agh = 0.f;

    for (int kc = 0; kc < 8; ++kc) {
        const int k0 = kc * 128;
        __syncthreads();
        for (int idx = tid; idx < NB * 128; idx += 256) {
            const int r = idx >> 7, c = idx & 127;
            float vi;
            if (isX) {
                const size_t xo = (size_t)r * NS * NI + (size_t)t * NI + (k0 + c);
                vi = f32m ? ((const float*)x)[xo] : bf2f(((const unsigned short*)x)[xo]);
            } else {
                vi = inp[r * NH + k0 + c];
            }
            s_in[r][c] = vi;
            s_h [r][c] = hprev[r * NH + k0 + c];
        }
        __syncthreads();

        const int cbase = ks * 32;
#pragma unroll
        for (int q8 = 0; q8 < 4; ++q8) {
            const int c = cbase + q8 * 8;
            const int k = k0 + c;
            float wz[8], wr[8], wg[8], vz[8], vr[8], vg[8];
            if (f32m) {
                load8f((const float*)Wzi_ + wIl + k, wz);
                load8f((const float*)Wri_ + wIl + k, wr);
                load8f((const float*)Wgi_ + wIl + k, wg);
                load8f((const float*)Wzh_ + wIl + k, vz);
                load8f((const float*)Wrh_ + wIl + k, vr);
                load8f((const float*)Wgh_ + wIl + k, vg);
            } else {
                load8h((const unsigned short*)Wzi_ + wIl + k, wz);
                load8h((const unsigned short*)Wri_ + wIl + k, wr);
                load8h((const unsigned short*)Wgi_ + wIl + k, wg);
                load8h((const unsigned short*)Wzh_ + wIl + k, vz);
                load8h((const unsigned short*)Wrh_ + wIl + k, vr);
                load8h((const unsigned short*)Wgh_ + wIl + k, vg);
            }
            float ai[8], ah[8];
#pragma unroll
            for (int q = 0; q < 8; ++q) { ai[q] = s_in[b][c + q]; ah[q] = s_h[b][c + q]; }
#pragma unroll
            for (int q = 0; q < 8; ++q) {
                azi = fmaf(wz[q], ai[q], azi);
                ari = fmaf(wr[q], ai[q], ari);
                agi = fmaf(wg[q], ai[q], agi);
                azh = fmaf(vz[q], ah[q], azh);
                arh = fmaf(vr[q], ah[q], arh);
                agh = fmaf(vg[q], ah[q], agh);
            }
        }
    }

    s_red[tid][0] = azi; s_red[tid][1] = azh; s_red[tid][2] = ari;
    s_red[tid][3] = arh; s_red[tid][4] = agi; s_red[tid][5] = agh;
    __syncthreads();

    if (ks == 0) {
#pragma unroll
        for (int w = 1; w < 4; ++w) {
            azi += s_red[tid + 64*w][0]; azh += s_red[tid + 64*w][1];
            ari += s_red[tid + 64*w][2]; arh += s_red[tid + 64*w][3];
            agi += s_red[tid + 64*w][4]; agh += s_red[tid + 64*w][5];
        }
        const float bz = f32m ? ((const float*)bzh_)[bl] : bf2f(((const unsigned short*)bzh_)[bl]);
        const float br = f32m ? ((const float*)brh_)[bl] : bf2f(((const unsigned short*)brh_)[bl]);
        const float bg = f32m ? ((const float*)bgh_)[bl] : bf2f(((const unsigned short*)bgh_)[bl]);
        const float z = 1.f / (1.f + expf(-(azi + azh + bz)));
        const float r = 1.f / (1.f + expf(-(ari + arh + br)));
        const float g = tanhf(agi + r * (agh + bg));
        const float hp = hprev[b * NH + j];
        const float hn = z * hp + (1.f - z) * g;
        hnew[b * NH + j] = hn;
        if (h2out) {
            const size_t off = (size_t)b * NS * NO + (size_t)t * NO + j;
            if (f32m) ((float*)h2out)[off] = hn;
            else      ((unsigned short*)h2out)[off] = f2bf(hn);
        }
    }
}

__global__ __launch_bounds__(256) void out_gemm(
    void* __restrict__ out, const void* __restrict__ Wout, const void* __restrict__ bout,
    const int* __restrict__ flagp)
{
    __shared__ float s_a[8][1024];
    const int f32m = *flagp;
    const int tid = threadIdx.x;
    const size_t row0 = (size_t)blockIdx.x * 8;

    for (int idx = tid; idx < 8 * 1024; idx += 256) {
        const int r = idx >> 10, c = idx & 1023;
        const size_t off = (row0 + r) * NO + c;
        s_a[r][c] = f32m ? ((const float*)out)[off] : bf2f(((const unsigned short*)out)[off]);
    }
    __syncthreads();

    float acc[4][8];
#pragma unroll
    for (int m = 0; m < 4; ++m)
#pragma unroll
        for (int r = 0; r < 8; ++r) acc[m][r] = 0.f;

    for (int k8 = 0; k8 < 128; ++k8) {
        const int k = k8 * 8;
        float wf[4][8];
#pragma unroll
        for (int m = 0; m < 4; ++m) {
            const size_t wo = (size_t)(tid + 256*m) * NH + k;
            if (f32m) load8f((const float*)Wout + wo, wf[m]);
            else      load8h((const unsigned short*)Wout + wo, wf[m]);
        }
#pragma unroll
        for (int r = 0; r < 8; ++r) {
            float a[8];
#pragma unroll
            for (int q = 0; q < 8; ++q) a[q] = s_a[r][k + q];
#pragma unroll
            for (int m = 0; m < 4; ++m)
#pragma unroll
                for (int q = 0; q < 8; ++q)
                    acc[m][r] = fmaf(wf[m][q], a[q], acc[m][r]);
        }
    }

#pragma unroll
    for (int m = 0; m < 4; ++m) {
        const int jj = tid + 256*m;
        const float bj = f32m ? ((const float*)bout)[jj] : bf2f(((const unsigned short*)bout)[jj]);
#pragma unroll
        for (int r = 0; r < 8; ++r) {
            const size_t off = (row0 + r) * NO + jj;
            const float v = acc[m][r] + bj;
            if (f32m) ((float*)out)[off] = v;
            else      ((unsigned short*)out)[off] = f2bf(v);
        }
    }
}

__global__ void tail_kernel(const float* __restrict__ st, void* __restrict__ out,
                            const int* __restrict__ flagp)
{
    const int f32m = *flagp;
    const int idx = blockIdx.x * 256 + threadIdx.x;
    if (idx >= NL * NB * NH) return;
    const int l = idx >> 15;
    const int b = (idx >> 10) & 31;
    const int j = idx & 1023;
    const size_t dst = (size_t)NB * NS * NO + (size_t)b * NL * NH + (size_t)l * NH + j;
    if (f32m) ((float*)out)[dst] = st[idx];
    else      ((unsigned short*)out)[dst] = f2bf(st[idx]);
}

// ---------------- host ----------------
extern "C" void kernel_launch(void* const* d_in, const int* in_sizes, int n_in,
                              void* d_out, int out_size, void* d_ws, size_t ws_size,
                              hipStream_t stream)
{
    const void* x    = d_in[0];
    const void* h0   = d_in[1];
    const void* Wzi  = d_in[2];
    const void* Wzh  = d_in[3];
    const void* bzh  = d_in[4];
    const void* Wri  = d_in[5];
    const void* Wrh  = d_in[6];
    const void* brh  = d_in[7];
    const void* Wgi  = d_in[8];
    const void* Wgh  = d_in[9];
    const void* bgh  = d_in[10];
    const void* Wout = d_in[11];
    const void* bout = d_in[12];

    // ws layout
    char* w = (char*)d_ws;
    float* st            = (float*)w;                       // [2][3][32][1024] f32
    int*   flag          = (int*)(w + 786432);
    unsigned int* act    = (unsigned int*)(w + 786464);     // [3][2][32][1024] packed hi|lo, ends 1,572,896
    unsigned int* gflags = (unsigned int*)(w + 1572992);    // 256 flag lines + 1 gen line, ends 1,605,888
    auto stp = [&](int p, int l) { return st + ((size_t)(p * NL + l)) * NB * NH; };

    detect_kernel<<<1, 256, 0, stream>>>((const unsigned int*)x, flag);
    init_act<<<(NL*NB*NH + 255)/256, 256, 0, stream>>>(h0, act, gflags, flag);

    (void)hipFuncSetAttribute((const void*)gru_persist,
                              hipFuncAttributeMaxDynamicSharedMemorySize, LDSB);
    (void)hipGetLastError();   // clear
    gru_persist<<<WGN, BLK, LDSB, stream>>>(
        x, Wzi, Wzh, bzh, Wri, Wrh, brh, Wgi, Wgh, bgh,
        d_out, act, st /* final h */, flag, gflags);
    hipError_t perr = hipGetLastError();

    if (perr != hipSuccess) {
        init_kernel<<<(NL*NB*NH + 255)/256, 256, 0, stream>>>(h0, st, flag);
        for (int t = 0; t < NS; ++t) {
            const int pr = t & 1, pw = 1 - pr;
            for (int l = 0; l < NL; ++l) {
                gru_layer<<<512, 256, 0, stream>>>(
                    x,
                    l == 0 ? st : stp(pw, l - 1),
                    stp(pr, l),
                    stp(pw, l),
                    l == 2 ? d_out : (void*)nullptr,
                    Wzi, Wzh, bzh, Wri, Wrh, brh, Wgi, Wgh, bgh,
                    flag, t | (l << 16), l == 0 ? 1 : 0);
            }
        }
    }

    out_gemm<<<NB * NS / 8, 256, 0, stream>>>(d_out, Wout, bout, flag);
    tail_kernel<<<(NL*NB*NH + 255)/256, 256, 0, stream>>>(st, d_out, flag);
}

// Round 4
// 13626.855 us; speedup vs baseline: 2.8012x; 1.0456x over previous
//
#include <hip/hip_runtime.h>
#include <hip/hip_bf16.h>

// MultilayerGRU: B=32 S=512 I=H=O=1024 L=3.
// Round 8: kill the two remaining serialization storms in the barrier phase.
//  (a) per-XCD inv ELECTION: was 32 L2-invs per XCD per step (each WG fenced),
//      each occupying the L2 maintenance pipe and wiping neighbors' fills.
//      Now: first WG per XCD (atomicExch claim, parity slot) does ONE
//      agent-acquire fence (L1+L2 inv) + publishes done[xcd]; the other 31
//      poll done and do an L1-only buffer_inv (their CU's L1 can be stale;
//      L1 flash-inv is local/fast). XCD identity via s_getreg hwreg(20)
//      (HW_REG_XCC_ID, measured 0..7 on MI355X).
//  (b) gen BROADCAST TREE: 255 WGs polled ONE gen line at L3 -> same-line
//      serialization made discovery cost several us. WG0 now writes 16 gen
//      copies; WG w polls copy w>>4 (<=16 pollers/line).

#define NB 32
#define NS 512
#define NI 1024
#define NH 1024
#define NL 3
#define NO 1024

#define WGN 256
#define BLK 512
#define SLOTS 12
#define RPB 2096                 // weight row pitch bytes; 524 dwords == 12 mod 32 -> 2-way max (free)
#define ZROW 72                  // zero-row index
#define COFF (73 * RPB)          // 153,008
#define CPITCH 33                // 33 dwords == 1 mod 32 -> conflict-free
#define LDSB (COFF + 48 * CPITCH * 4)   // 159,344 <= 163,840

// gflags dword-index layout (each logical flag on its own 128B line):
#define GENB   (WGN * 32)            // 8192: 16 gen-copy lines
#define CLAIMB (GENB + 16 * 32)      // 8704: claim[xcd][par] lines (16)
#define DONEB  (CLAIMB + 16 * 32)    // 9216: done[xcd] lines (8) -> end 9472
#define GFL_N  9472

using short8 = __attribute__((ext_vector_type(8))) short;
using floatx4 = __attribute__((ext_vector_type(4))) float;

static __device__ __forceinline__ float bf2f(unsigned short u) {
    union { unsigned int i; float f; } v;
    v.i = ((unsigned int)u) << 16;
    return v.f;
}

static __device__ __forceinline__ unsigned short f2bf(float f) {
    __hip_bfloat16 h = __float2bfloat16(f);   // RNE
    union { __hip_bfloat16 h; unsigned short u; } v;
    v.h = h;
    return v.u;
}

static __device__ __forceinline__ void load8h(const unsigned short* p, float w[8]) {
    uint4 q = *(const uint4*)p;
    unsigned int u[4] = {q.x, q.y, q.z, q.w};
#pragma unroll
    for (int i = 0; i < 4; ++i) {
        w[2*i]   = __uint_as_float(u[i] << 16);
        w[2*i+1] = __uint_as_float(u[i] & 0xffff0000u);
    }
}

static __device__ __forceinline__ void load8f(const float* p, float w[8]) {
    float4 a = *(const float4*)p;
    float4 b = *(const float4*)(p + 4);
    w[0]=a.x; w[1]=a.y; w[2]=a.z; w[3]=a.w;
    w[4]=b.x; w[5]=b.y; w[6]=b.z; w[7]=b.w;
}

static __device__ __forceinline__ int xcc_id() {
    unsigned v;
    asm volatile("s_getreg_b32 %0, hwreg(20, 0, 32)" : "=s"(v));   // HW_REG_XCC_ID
    return (int)(v & 7);
}

// ---------------- dtype detection ----------------
__global__ void detect_kernel(const unsigned int* __restrict__ xw, int* __restrict__ flag) {
    __shared__ int cnt[256];
    int c = 0;
    for (int i = threadIdx.x; i < 1024; i += 256) {
        unsigned int e = (xw[i] >> 7) & 0xFFu;
        if (e >= 0x78u && e <= 0x84u) c++;
    }
    cnt[threadIdx.x] = c;
    __syncthreads();
    if (threadIdx.x == 0) {
        int s = 0;
        for (int i = 0; i < 256; ++i) s += cnt[i];
        *flag = (s < 512) ? 1 : 0;
    }
}

// ---------------- init: h0 -> act parity-1 packed (hi<<16|lo); zero flags ----
__global__ void init_act(const void* __restrict__ h0,
                         unsigned int* __restrict__ act,
                         unsigned int* __restrict__ gflags,
                         const int* __restrict__ flagp) {
    const int f32m = *flagp;
    const int idx = blockIdx.x * 256 + threadIdx.x;  // l*32768 + b*1024 + j
    if (idx < GFL_N) gflags[idx] = 0u;
    if (idx >= NL * NB * NH) return;
    const int l = idx >> 15;
    const int b = (idx >> 10) & 31;
    const int j = idx & 1023;
    const size_t src = (size_t)b * NL * NH + (size_t)l * NH + j;
    float v = f32m ? ((const float*)h0)[src] : bf2f(((const unsigned short*)h0)[src]);
    unsigned short hi = f2bf(v);
    unsigned short lo = f2bf(v - bf2f(hi));
    const size_t dst = ((size_t)(l * 2 + 1) * NB + b) * NH + j;   // parity 1
    act[dst] = ((unsigned int)hi << 16) | lo;
}

// ---------------- persistent pipeline kernel ----------------
__global__ __launch_bounds__(BLK, 2) void gru_persist(
    const void* __restrict__ x,
    const void* __restrict__ Wzi_, const void* __restrict__ Wzh_, const void* __restrict__ bzh_,
    const void* __restrict__ Wri_, const void* __restrict__ Wrh_, const void* __restrict__ brh_,
    const void* __restrict__ Wgi_, const void* __restrict__ Wgh_, const void* __restrict__ bgh_,
    void* __restrict__ dout,
    unsigned int* __restrict__ act,
    float* __restrict__ stfin,
    const int* __restrict__ flagp,
    unsigned int* __restrict__ gflags)
{
    extern __shared__ char lds[];
    float* clds = (float*)(lds + COFF);

    const int f32m = *flagp;
    const int tid  = threadIdx.x;
    const int wg   = blockIdx.x;
    const int lane = tid & 63;
    const int wid  = tid >> 6;          // 0..7
    const int Mtile = wid & 1;
    const int khalf = wid >> 1;         // 0..3 -> 256-col K slice
    const int n16  = lane & 15;
    const int q4   = lane >> 4;

    const int slot0 = wg * SLOTS;

    // ---- preload weights into LDS (bf16) ----
    {
        const void* Wmats[6] = {Wzi_, Wzh_, Wri_, Wrh_, Wgi_, Wgh_};
        if (f32m) {
            for (int idx = tid; idx < 72 * 256; idx += BLK) {
                const int r = idx >> 8, c4 = (idx & 255) * 4;
                const int slot = slot0 + r / 6, g = r % 6;
                const int layer = slot >> 10, j = slot & 1023;
                const float* src = (const float*)Wmats[g] + (size_t)layer * NH * NI + (size_t)j * NI + c4;
                float4 f = *(const float4*)src;
                unsigned short* dst = (unsigned short*)(lds + r * RPB + c4 * 2);
                dst[0] = f2bf(f.x); dst[1] = f2bf(f.y); dst[2] = f2bf(f.z); dst[3] = f2bf(f.w);
            }
        } else {
            for (int idx = tid; idx < 72 * 128; idx += BLK) {
                const int r = idx >> 7, c8 = (idx & 127) * 8;
                const int slot = slot0 + r / 6, g = r % 6;
                const int layer = slot >> 10, j = slot & 1023;
                const unsigned short* src = (const unsigned short*)Wmats[g] + (size_t)layer * NH * NI + (size_t)j * NI + c8;
                *(uint4*)(lds + r * RPB + c8 * 2) = *(const uint4*)src;
            }
        }
        unsigned int* z = (unsigned int*)(lds + ZROW * RPB);
        for (int c = tid; c < RPB / 4; c += BLK) z[c] = 0u;
    }

    // ---- epilogue thread state (tid < 384): biases + register h_prev ----
    int eci = 0, eb = 0, elg = 0, ej = 0;
    float ebz = 0.f, ebr = 0.f, ebg = 0.f, ehp = 0.f;
    if (tid < NB * SLOTS) {
        eci = tid % SLOTS; eb = tid / SLOTS;
        const int slot = slot0 + eci;
        elg = slot >> 10; ej = slot & 1023;
        const size_t bidx = (size_t)elg * NH + ej;
        if (f32m) {
            ebz = ((const float*)bzh_)[bidx];
            ebr = ((const float*)brh_)[bidx];
            ebg = ((const float*)bgh_)[bidx];
        } else {
            ebz = bf2f(((const unsigned short*)bzh_)[bidx]);
            ebr = bf2f(((const unsigned short*)brh_)[bidx]);
            ebg = bf2f(((const unsigned short*)bgh_)[bidx]);
        }
    }

    // ---- layer groups (slot range may straddle one layer boundary) ----
    const int lay0 = slot0 >> 10;
    const int lay1 = (slot0 + SLOTS - 1) >> 10;
    const int ngroups = (lay0 == lay1) ? 1 : 2;
    const int n0 = (ngroups == 1) ? SLOTS : (1024 - (slot0 & 1023));

    const int myxcd = xcc_id();

    __syncthreads();

    for (int s = 0; s < NS + NL - 1; ++s) {
        for (int i = tid; i < 48 * CPITCH; i += BLK) clds[i] = 0.f;
        __syncthreads();

        floatx4 acc[3];
#pragma unroll
        for (int nt = 0; nt < 3; ++nt) acc[nt] = (floatx4){0.f, 0.f, 0.f, 0.f};

        for (int grp = 0; grp < ngroups; ++grp) {
            const int lg = (grp == 0) ? lay0 : lay1;
            const int t = s - lg;
            if (t < 0 || t >= NS) continue;
            const int ntLo = (grp == 0) ? 0 : ((4 * n0) >> 4);
            const int ntHi = (grp == 0) ? (ngroups == 1 ? 2 : ((4 * n0) >> 4) - 1) : 2;
            const int mb = Mtile * 16 + n16;

            for (int phase = 0; phase < 2; ++phase) {
                int brow[3];
#pragma unroll
                for (int nt = 0; nt < 3; ++nt) {
                    const int v = nt * 16 + n16;
                    const int ci = v >> 2, g = v & 3;
                    int r;
                    if (phase == 0) r = (g == 3) ? ZROW : ci * 6 + ((g == 2) ? 4 : g * 2);
                    else            r = (g == 2) ? ZROW : ci * 6 + ((g == 3) ? 5 : g * 2 + 1);
                    brow[nt] = r;
                }

                const bool isx = (phase == 0 && lg == 0);
                const bool dolo = isx ? (f32m != 0) : true;

                // hoist all A-frags for this phase into registers
                short8 AH[8], AL[8];
                if (isx) {
                    if (f32m) {
                        const float* xb = (const float*)x + ((size_t)mb * NS + t) * NI + khalf * 256 + q4 * 8;
#pragma unroll
                        for (int ks = 0; ks < 8; ++ks) {
                            float f[8];
                            load8f(xb + ks * 32, f);
#pragma unroll
                            for (int e = 0; e < 8; ++e) {
                                unsigned short h = f2bf(f[e]);
                                AH[ks][e] = (short)h;
                                AL[ks][e] = (short)f2bf(f[e] - bf2f(h));
                            }
                        }
                    } else {
                        const unsigned short* xb = (const unsigned short*)x + ((size_t)mb * NS + t) * NI + khalf * 256 + q4 * 8;
#pragma unroll
                        for (int ks = 0; ks < 8; ++ks)
                            AH[ks] = *(const short8*)(xb + ks * 32);
                    }
                } else {
                    const int src_l = (phase == 0) ? lg - 1 : lg;
                    const int src_p = (phase == 0) ? (t & 1) : ((t - 1) & 1);
                    const size_t ab = ((size_t)(src_l * 2 + src_p) * NB + mb) * NH + khalf * 256 + q4 * 8;
                    // PLAIN cached loads (L1/L2); coherence via the per-step
                    // per-XCD inv after the barrier below.
                    const uint4* ap = (const uint4*)(act + ab);
                    uint4 qq[16];
#pragma unroll
                    for (int ks = 0; ks < 8; ++ks) {
                        qq[2*ks]   = ap[ks * 8];       // u32 elems ks*32 + 0..3
                        qq[2*ks+1] = ap[ks * 8 + 1];   // u32 elems ks*32 + 4..7
                    }
#pragma unroll
                    for (int ks = 0; ks < 8; ++ks) {
                        unsigned int c[8] = {qq[2*ks].x, qq[2*ks].y, qq[2*ks].z, qq[2*ks].w,
                                             qq[2*ks+1].x, qq[2*ks+1].y, qq[2*ks+1].z, qq[2*ks+1].w};
#pragma unroll
                        for (int e = 0; e < 8; ++e) {
                            AH[ks][e] = (short)(c[e] >> 16);
                            AL[ks][e] = (short)(c[e] & 0xffffu);
                        }
                    }
                }

#pragma unroll
                for (int ks = 0; ks < 8; ++ks) {
                    const int k0 = khalf * 256 + ks * 32;
#pragma unroll
                    for (int nt = 0; nt < 3; ++nt) {
                        if (nt < ntLo || nt > ntHi) continue;
                        const short8 bf = *(const short8*)(lds + brow[nt] * RPB + k0 * 2 + q4 * 16);
                        acc[nt] = __builtin_amdgcn_mfma_f32_16x16x32_bf16(AH[ks], bf, acc[nt], 0, 0, 0);
                        if (dolo)
                            acc[nt] = __builtin_amdgcn_mfma_f32_16x16x32_bf16(AL[ks], bf, acc[nt], 0, 0, 0);
                    }
                }
            }
        }

        // dump accumulators (C/D: col=lane&15, row=q4*4+reg)
        {
            const int mbase = Mtile * 16 + q4 * 4;
#pragma unroll
            for (int nt = 0; nt < 3; ++nt) {
                const int vcol = nt * 16 + n16;
#pragma unroll
                for (int r = 0; r < 4; ++r)
                    atomicAdd(&clds[vcol * CPITCH + mbase + r], acc[nt][r]);
            }
        }
        __syncthreads();

        // epilogue: one thread per (col, batch)
        if (tid < NB * SLOTS) {
            const int t = s - elg;
            if (t >= 0 && t < NS) {
                const float zp = clds[(eci * 4 + 0) * CPITCH + eb];
                const float rp = clds[(eci * 4 + 1) * CPITCH + eb];
                const float gi = clds[(eci * 4 + 2) * CPITCH + eb];
                const float gh = clds[(eci * 4 + 3) * CPITCH + eb];
                float hp;
                if (t == 0) {
                    const size_t hoff = ((size_t)(elg * 2 + 1) * NB + eb) * NH + ej;
                    const unsigned int pv = act[hoff];   // init_act wrote it pre-kernel
                    hp = bf2f((unsigned short)(pv >> 16)) + bf2f((unsigned short)(pv & 0xffffu));
                } else {
                    hp = ehp;
                }
                const float z = 1.f / (1.f + expf(-(zp + ebz)));
                const float r = 1.f / (1.f + expf(-(rp + ebr)));
                const float g = tanhf(gi + r * (gh + ebg));
                const float hn = z * hp + (1.f - z) * g;
                ehp = hn;
                const unsigned short hi = f2bf(hn);
                const unsigned short lo = f2bf(hn - bf2f(hi));
                const size_t woff = ((size_t)(elg * 2 + (t & 1)) * NB + eb) * NH + ej;
                // sc1 write-through store: lands in L3, never dirty in L2
                __hip_atomic_store(&act[woff], ((unsigned int)hi << 16) | lo,
                                   __ATOMIC_RELAXED, __HIP_MEMORY_SCOPE_AGENT);
                if (elg == 2) {
                    const size_t o = ((size_t)eb * NS + t) * NO + ej;
                    if (f32m) ((float*)dout)[o] = hn;
                    else      ((unsigned short*)dout)[o] = f2bf(hn);
                }
                if (t == NS - 1)
                    stfin[((size_t)elg * NB + eb) * NH + ej] = hn;
            }
        }

        // ---- barrier: arrivals -> master -> gen tree -> per-XCD inv election
        __syncthreads();   // drains each wave's sc1 stores (vmcnt 0) before publish
        if (tid == 0)
            __hip_atomic_store(&gflags[wg * 32], (unsigned int)(s + 1),
                               __ATOMIC_RELAXED, __HIP_MEMORY_SCOPE_AGENT);
        if (wg == 0) {
            // master: 4 waves poll all 256 per-WG flags (1 lane : 1 flag)
            if (tid < WGN) {
                while (__hip_atomic_load(&gflags[tid * 32], __ATOMIC_RELAXED,
                                         __HIP_MEMORY_SCOPE_AGENT) <= (unsigned int)s)
                    __builtin_amdgcn_s_sleep(1);
            }
            __syncthreads();   // all 256 arrivals observed
            if (tid < 16)      // broadcast tree: 16 gen copies, <=16 pollers each
                __hip_atomic_store(&gflags[GENB + tid * 32], (unsigned int)(s + 1),
                                   __ATOMIC_RELAXED, __HIP_MEMORY_SCOPE_AGENT);
        } else {
            if (tid == 0) {
                while (__hip_atomic_load(&gflags[GENB + (wg >> 4) * 32], __ATOMIC_RELAXED,
                                         __HIP_MEMORY_SCOPE_AGENT) <= (unsigned int)s)
                    __builtin_amdgcn_s_sleep(1);
            }
        }
        // per-XCD single L2 inv; everyone flash-invs their own CU's L1
        if (tid == 0) {
            const unsigned tag = (unsigned)(s + 1);
            unsigned* claim = &gflags[CLAIMB + (myxcd * 2 + (s & 1)) * 32];
            unsigned old = __hip_atomic_exchange(claim, tag,
                                                 __ATOMIC_RELAXED, __HIP_MEMORY_SCOPE_AGENT);
            if (old != tag) {
                // winner: full acquire (waits + L1 inv + this XCD's L2 inv)
                __builtin_amdgcn_fence(__ATOMIC_ACQUIRE, "agent");
                __hip_atomic_store(&gflags[DONEB + myxcd * 32], tag,
                                   __ATOMIC_RELAXED, __HIP_MEMORY_SCOPE_AGENT);
            } else {
                // loser: wait for winner's L2 inv, then L1-only flash inv
                while (__hip_atomic_load(&gflags[DONEB + myxcd * 32], __ATOMIC_RELAXED,
                                         __HIP_MEMORY_SCOPE_AGENT) <= (unsigned int)s)
                    __builtin_amdgcn_s_sleep(1);
                asm volatile("buffer_inv" ::: "memory");
            }
            __builtin_amdgcn_sched_barrier(0);
        }
        __syncthreads();   // no wave issues next-step loads before tid0's inv
    }
}

// ---------------- fallback kernels (round-2, proven) ----------------
__global__ void init_kernel(const void* __restrict__ h0, float* __restrict__ st,
                            const int* __restrict__ flagp) {
    const int f32m = *flagp;
    const int idx = blockIdx.x * 256 + threadIdx.x;
    if (idx >= NL * NB * NH) return;
    const int l = idx >> 15;
    const int b = (idx >> 10) & 31;
    const int j = idx & 1023;
    const size_t src = (size_t)b * NL * NH + (size_t)l * NH + j;
    st[idx] = f32m ? ((const float*)h0)[src] : bf2f(((const unsigned short*)h0)[src]);
}

__global__ __launch_bounds__(256) void gru_layer(
    const void*  __restrict__ x,
    const float* __restrict__ inp,
    const float* __restrict__ hprev,
    float*       __restrict__ hnew,
    void*        __restrict__ h2out,
    const void* __restrict__ Wzi_, const void* __restrict__ Wzh_, const void* __restrict__ bzh_,
    const void* __restrict__ Wri_, const void* __restrict__ Wrh_, const void* __restrict__ brh_,
    const void* __restrict__ Wgi_, const void* __restrict__ Wgh_, const void* __restrict__ bgh_,
    const int* __restrict__ flagp, int tl, int isX)
{
    __shared__ float s_in[NB][129];
    __shared__ float s_h [NB][129];
    __shared__ float s_red[256][6];

    const int f32m = *flagp;
    const int t = tl & 0xFFFF;
    const int l = tl >> 16;
    const int tid = threadIdx.x;
    const int b   = tid & 31;
    const int jl  = (tid >> 5) & 1;
    const int ks  = tid >> 6;
    const int j   = blockIdx.x * 2 + jl;

    const size_t wIl = (size_t)l * NH * NI + (size_t)j * NI;
    const size_t bl  = (size_t)l * NH + j;

    float azi = 0.f, azh = 0.f, ari = 0.f, arh = 0.f, agi = 0.f, agh = 0.f;

    for (int kc = 0; kc < 8; ++kc) {
        const int k0 = kc * 128;
        __syncthreads();
        for (int idx = tid; idx < NB * 128; idx += 256) {
            const int r = idx >> 7, c = idx & 127;
            float vi;
            if (isX) {
                const size_t xo = (size_t)r * NS * NI + (size_t)t * NI + (k0 + c);
                vi = f32m ? ((const float*)x)[xo] : bf2f(((const unsigned short*)x)[xo]);
            } else {
                vi = inp[r * NH + k0 + c];
            }
            s_in[r][c] = vi;
            s_h [r][c] = hprev[r * NH + k0 + c];
        }
        __syncthreads();

        const int cbase = ks * 32;
#pragma unroll
        for (int q8 = 0; q8 < 4; ++q8) {
            const int c = cbase + q8 * 8;
            const int k = k0 + c;
            float wz[8], wr[8], wg[8], vz[8], vr[8], vg[8];
            if (f32m) {
                load8f((const float*)Wzi_ + wIl + k, wz);
                load8f((const float*)Wri_ + wIl + k, wr);
                load8f((const float*)Wgi_ + wIl + k, wg);
                load8f((const float*)Wzh_ + wIl + k, vz);
                load8f((const float*)Wrh_ + wIl + k, vr);
                load8f((const float*)Wgh_ + wIl + k, vg);
            } else {
                load8h((const unsigned short*)Wzi_ + wIl + k, wz);
                load8h((const unsigned short*)Wri_ + wIl + k, wr);
                load8h((const unsigned short*)Wgi_ + wIl + k, wg);
                load8h((const unsigned short*)Wzh_ + wIl + k, vz);
                load8h((const unsigned short*)Wrh_ + wIl + k, vr);
                load8h((const unsigned short*)Wgh_ + wIl + k, vg);
            }
            float ai[8], ah[8];
#pragma unroll
            for (int q = 0; q < 8; ++q) { ai[q] = s_in[b][c + q]; ah[q] = s_h[b][c + q]; }
#pragma unroll
            for (int q = 0; q < 8; ++q) {
                azi = fmaf(wz[q], ai[q], azi);
                ari = fmaf(wr[q], ai[q], ari);
                agi = fmaf(wg[q], ai[q], agi);
                azh = fmaf(vz[q], ah[q], azh);
                arh = fmaf(vr[q], ah[q], arh);
                agh = fmaf(vg[q], ah[q], agh);
            }
        }
    }

    s_red[tid][0] = azi; s_red[tid][1] = azh; s_red[tid][2] = ari;
    s_red[tid][3] = arh; s_red[tid][4] = agi; s_red[tid][5] = agh;
    __syncthreads();

    if (ks == 0) {
#pragma unroll
        for (int w = 1; w < 4; ++w) {
            azi += s_red[tid + 64*w][0]; azh += s_red[tid + 64*w][1];
            ari += s_red[tid + 64*w][2]; arh += s_red[tid + 64*w][3];
            agi += s_red[tid + 64*w][4]; agh += s_red[tid + 64*w][5];
        }
        const float bz = f32m ? ((const float*)bzh_)[bl] : bf2f(((const unsigned short*)bzh_)[bl]);
        const float br = f32m ? ((const float*)brh_)[bl] : bf2f(((const unsigned short*)brh_)[bl]);
        const float bg = f32m ? ((const float*)bgh_)[bl] : bf2f(((const unsigned short*)bgh_)[bl]);
        const float z = 1.f / (1.f + expf(-(azi + azh + bz)));
        const float r = 1.f / (1.f + expf(-(ari + arh + br)));
        const float g = tanhf(agi + r * (agh + bg));
        const float hp = hprev[b * NH + j];
        const float hn = z * hp + (1.f - z) * g;
        hnew[b * NH + j] = hn;
        if (h2out) {
            const size_t off = (size_t)b * NS * NO + (size_t)t * NO + j;
            if (f32m) ((float*)h2out)[off] = hn;
            else      ((unsigned short*)h2out)[off] = f2bf(hn);
        }
    }
}

__global__ __launch_bounds__(256) void out_gemm(
    void* __restrict__ out, const void* __restrict__ Wout, const void* __restrict__ bout,
    const int* __restrict__ flagp)
{
    __shared__ float s_a[8][1024];
    const int f32m = *flagp;
    const int tid = threadIdx.x;
    const size_t row0 = (size_t)blockIdx.x * 8;

    for (int idx = tid; idx < 8 * 1024; idx += 256) {
        const int r = idx >> 10, c = idx & 1023;
        const size_t off = (row0 + r) * NO + c;
        s_a[r][c] = f32m ? ((const float*)out)[off] : bf2f(((const unsigned short*)out)[off]);
    }
    __syncthreads();

    float acc[4][8];
#pragma unroll
    for (int m = 0; m < 4; ++m)
#pragma unroll
        for (int r = 0; r < 8; ++r) acc[m][r] = 0.f;

    for (int k8 = 0; k8 < 128; ++k8) {
        const int k = k8 * 8;
        float wf[4][8];
#pragma unroll
        for (int m = 0; m < 4; ++m) {
            const size_t wo = (size_t)(tid + 256*m) * NH + k;
            if (f32m) load8f((const float*)Wout + wo, wf[m]);
            else      load8h((const unsigned short*)Wout + wo, wf[m]);
        }
#pragma unroll
        for (int r = 0; r < 8; ++r) {
            float a[8];
#pragma unroll
            for (int q = 0; q < 8; ++q) a[q] = s_a[r][k + q];
#pragma unroll
            for (int m = 0; m < 4; ++m)
#pragma unroll
                for (int q = 0; q < 8; ++q)
                    acc[m][r] = fmaf(wf[m][q], a[q], acc[m][r]);
        }
    }

#pragma unroll
    for (int m = 0; m < 4; ++m) {
        const int jj = tid + 256*m;
        const float bj = f32m ? ((const float*)bout)[jj] : bf2f(((const unsigned short*)bout)[jj]);
#pragma unroll
        for (int r = 0; r < 8; ++r) {
            const size_t off = (row0 + r) * NO + jj;
            const float v = acc[m][r] + bj;
            if (f32m) ((float*)out)[off] = v;
            else      ((unsigned short*)out)[off] = f2bf(v);
        }
    }
}

__global__ void tail_kernel(const float* __restrict__ st, void* __restrict__ out,
                            const int* __restrict__ flagp)
{
    const int f32m = *flagp;
    const int idx = blockIdx.x * 256 + threadIdx.x;
    if (idx >= NL * NB * NH) return;
    const int l = idx >> 15;
    const int b = (idx >> 10) & 31;
    const int j = idx & 1023;
    const size_t dst = (size_t)NB * NS * NO + (size_t)b * NL * NH + (size_t)l * NH + j;
    if (f32m) ((float*)out)[dst] = st[idx];
    else      ((unsigned short*)out)[dst] = f2bf(st[idx]);
}

// ---------------- host ----------------
extern "C" void kernel_launch(void* const* d_in, const int* in_sizes, int n_in,
                              void* d_out, int out_size, void* d_ws, size_t ws_size,
                              hipStream_t stream)
{
    const void* x    = d_in[0];
    const void* h0   = d_in[1];
    const void* Wzi  = d_in[2];
    const void* Wzh  = d_in[3];
    const void* bzh  = d_in[4];
    const void* Wri  = d_in[5];
    const void* Wrh  = d_in[6];
    const void* brh  = d_in[7];
    const void* Wgi  = d_in[8];
    const void* Wgh  = d_in[9];
    const void* bgh  = d_in[10];
    const void* Wout = d_in[11];
    const void* bout = d_in[12];

    // ws layout
    char* w = (char*)d_ws;
    float* st            = (float*)w;                       // [2][3][32][1024] f32
    int*   flag          = (int*)(w + 786432);
    unsigned int* act    = (unsigned int*)(w + 786464);     // [3][2][32][1024] packed hi|lo, ends 1,572,896
    unsigned int* gflags = (unsigned int*)(w + 1572992);    // GFL_N dwords, ends 1,610,880
    auto stp = [&](int p, int l) { return st + ((size_t)(p * NL + l)) * NB * NH; };

    detect_kernel<<<1, 256, 0, stream>>>((const unsigned int*)x, flag);
    init_act<<<(NL*NB*NH + 255)/256, 256, 0, stream>>>(h0, act, gflags, flag);

    (void)hipFuncSetAttribute((const void*)gru_persist,
                              hipFuncAttributeMaxDynamicSharedMemorySize, LDSB);
    (void)hipGetLastError();   // clear
    gru_persist<<<WGN, BLK, LDSB, stream>>>(
        x, Wzi, Wzh, bzh, Wri, Wrh, brh, Wgi, Wgh, bgh,
        d_out, act, st /* final h */, flag, gflags);
    hipError_t perr = hipGetLastError();

    if (perr != hipSuccess) {
        init_kernel<<<(NL*NB*NH + 255)/256, 256, 0, stream>>>(h0, st, flag);
        for (int t = 0; t < NS; ++t) {
            const int pr = t & 1, pw = 1 - pr;
            for (int l = 0; l < NL; ++l) {
                gru_layer<<<512, 256, 0, stream>>>(
                    x,
                    l == 0 ? st : stp(pw, l - 1),
                    stp(pr, l),
                    stp(pw, l),
                    l == 2 ? d_out : (void*)nullptr,
                    Wzi, Wzh, bzh, Wri, Wrh, brh, Wgi, Wgh, bgh,
                    flag, t | (l << 16), l == 0 ? 1 : 0);
            }
        }
    }

    out_gemm<<<NB * NS / 8, 256, 0, stream>>>(d_out, Wout, bout, flag);
    tail_kernel<<<(NL*NB*NH + 255)/256, 256, 0, stream>>>(st, d_out, flag);
}

// Round 5
// 12592.885 us; speedup vs baseline: 3.0312x; 1.0821x over previous
//
#include <hip/hip_runtime.h>
#include <hip/hip_bf16.h>

// MultilayerGRU: B=32 S=512 I=H=O=1024 L=3.
// Round 9: attack frontend/I$ thrash + layer-0 skew.
//  - gru_persist templated on <F32M>: two specialized kernels, each with
//    half the hot-loop code (f32m was a runtime branch duplicating every
//    load path). Both launched; wrong one exits after one flag read.
//    Rationale: per-step L2 inv also wipes INSTRUCTION lines out of L2, so
//    a fat loop body re-streams from L3 every iteration - a frontend stall
//    visible in NO counter (not VALUBusy/MfmaUtil/FETCH_SIZE).
//  - x-prefetch: layer-0 WGs load+convert x(t+1) into registers inside the
//    barrier window (after arrival publish, overlapping master/gen/inv
//    hops). Removes the slowest-WG skew term (64 f32 loads + ~400 VALU
//    convert) from the serial part of the step.
//  - clds read-then-zero: epilogue owner zeroes its 4 slots after reading;
//    per-step zero pass + one __syncthreads deleted (one-time zero at init).
//  - barrier + per-XCD inv election unchanged from round 8 (proven).

#define NB 32
#define NS 512
#define NI 1024
#define NH 1024
#define NL 3
#define NO 1024

#define WGN 256
#define BLK 512
#define SLOTS 12
#define RPB 2096                 // weight row pitch bytes; 524 dwords == 12 mod 32 -> 2-way max (free)
#define ZROW 72                  // zero-row index
#define COFF (73 * RPB)          // 153,008
#define CPITCH 33                // 33 dwords == 1 mod 32 -> conflict-free
#define LDSB (COFF + 48 * CPITCH * 4)   // 159,344 <= 163,840

// gflags dword-index layout (each logical flag on its own 128B line):
#define GENB   (WGN * 32)            // 8192: 16 gen-copy lines
#define CLAIMB (GENB + 16 * 32)      // 8704: claim[xcd][par] lines (16)
#define DONEB  (CLAIMB + 16 * 32)    // 9216: done[xcd] lines (8) -> end 9472
#define GFL_N  9472

using short8 = __attribute__((ext_vector_type(8))) short;
using floatx4 = __attribute__((ext_vector_type(4))) float;

static __device__ __forceinline__ float bf2f(unsigned short u) {
    union { unsigned int i; float f; } v;
    v.i = ((unsigned int)u) << 16;
    return v.f;
}

static __device__ __forceinline__ unsigned short f2bf(float f) {
    __hip_bfloat16 h = __float2bfloat16(f);   // RNE
    union { __hip_bfloat16 h; unsigned short u; } v;
    v.h = h;
    return v.u;
}

static __device__ __forceinline__ void load8h(const unsigned short* p, float w[8]) {
    uint4 q = *(const uint4*)p;
    unsigned int u[4] = {q.x, q.y, q.z, q.w};
#pragma unroll
    for (int i = 0; i < 4; ++i) {
        w[2*i]   = __uint_as_float(u[i] << 16);
        w[2*i+1] = __uint_as_float(u[i] & 0xffff0000u);
    }
}

static __device__ __forceinline__ void load8f(const float* p, float w[8]) {
    float4 a = *(const float4*)p;
    float4 b = *(const float4*)(p + 4);
    w[0]=a.x; w[1]=a.y; w[2]=a.z; w[3]=a.w;
    w[4]=b.x; w[5]=b.y; w[6]=b.z; w[7]=b.w;
}

static __device__ __forceinline__ int xcc_id() {
    unsigned v;
    asm volatile("s_getreg_b32 %0, hwreg(20, 0, 32)" : "=s"(v));   // HW_REG_XCC_ID
    return (int)(v & 7);
}

// ---------------- dtype detection ----------------
__global__ void detect_kernel(const unsigned int* __restrict__ xw, int* __restrict__ flag) {
    __shared__ int cnt[256];
    int c = 0;
    for (int i = threadIdx.x; i < 1024; i += 256) {
        unsigned int e = (xw[i] >> 7) & 0xFFu;
        if (e >= 0x78u && e <= 0x84u) c++;
    }
    cnt[threadIdx.x] = c;
    __syncthreads();
    if (threadIdx.x == 0) {
        int s = 0;
        for (int i = 0; i < 256; ++i) s += cnt[i];
        *flag = (s < 512) ? 1 : 0;
    }
}

// ---------------- init: h0 -> act parity-1 packed (hi<<16|lo); zero flags ----
__global__ void init_act(const void* __restrict__ h0,
                         unsigned int* __restrict__ act,
                         unsigned int* __restrict__ gflags,
                         const int* __restrict__ flagp) {
    const int f32m = *flagp;
    const int idx = blockIdx.x * 256 + threadIdx.x;  // l*32768 + b*1024 + j
    if (idx < GFL_N) gflags[idx] = 0u;
    if (idx >= NL * NB * NH) return;
    const int l = idx >> 15;
    const int b = (idx >> 10) & 31;
    const int j = idx & 1023;
    const size_t src = (size_t)b * NL * NH + (size_t)l * NH + j;
    float v = f32m ? ((const float*)h0)[src] : bf2f(((const unsigned short*)h0)[src]);
    unsigned short hi = f2bf(v);
    unsigned short lo = f2bf(v - bf2f(hi));
    const size_t dst = ((size_t)(l * 2 + 1) * NB + b) * NH + j;   // parity 1
    act[dst] = ((unsigned int)hi << 16) | lo;
}

// ---------------- persistent pipeline kernel (templated on dtype) ----------
template<int F32M>
__global__ __launch_bounds__(BLK, 2) void gru_persist(
    const void* __restrict__ x,
    const void* __restrict__ Wzi_, const void* __restrict__ Wzh_, const void* __restrict__ bzh_,
    const void* __restrict__ Wri_, const void* __restrict__ Wrh_, const void* __restrict__ brh_,
    const void* __restrict__ Wgi_, const void* __restrict__ Wgh_, const void* __restrict__ bgh_,
    void* __restrict__ dout,
    unsigned int* __restrict__ act,
    float* __restrict__ stfin,
    const int* __restrict__ flagp,
    unsigned int* __restrict__ gflags)
{
    if (*flagp != F32M) return;    // wrong-dtype instantiation: exit fast

    extern __shared__ char lds[];
    float* clds = (float*)(lds + COFF);

    const int tid  = threadIdx.x;
    const int wg   = blockIdx.x;
    const int lane = tid & 63;
    const int wid  = tid >> 6;          // 0..7
    const int Mtile = wid & 1;
    const int khalf = wid >> 1;         // 0..3 -> 256-col K slice
    const int n16  = lane & 15;
    const int q4   = lane >> 4;

    const int slot0 = wg * SLOTS;

    // ---- preload weights into LDS (bf16); zero clds once ----
    {
        const void* Wmats[6] = {Wzi_, Wzh_, Wri_, Wrh_, Wgi_, Wgh_};
        if (F32M) {
            for (int idx = tid; idx < 72 * 256; idx += BLK) {
                const int r = idx >> 8, c4 = (idx & 255) * 4;
                const int slot = slot0 + r / 6, g = r % 6;
                const int layer = slot >> 10, j = slot & 1023;
                const float* src = (const float*)Wmats[g] + (size_t)layer * NH * NI + (size_t)j * NI + c4;
                float4 f = *(const float4*)src;
                unsigned short* dst = (unsigned short*)(lds + r * RPB + c4 * 2);
                dst[0] = f2bf(f.x); dst[1] = f2bf(f.y); dst[2] = f2bf(f.z); dst[3] = f2bf(f.w);
            }
        } else {
            for (int idx = tid; idx < 72 * 128; idx += BLK) {
                const int r = idx >> 7, c8 = (idx & 127) * 8;
                const int slot = slot0 + r / 6, g = r % 6;
                const int layer = slot >> 10, j = slot & 1023;
                const unsigned short* src = (const unsigned short*)Wmats[g] + (size_t)layer * NH * NI + (size_t)j * NI + c8;
                *(uint4*)(lds + r * RPB + c8 * 2) = *(const uint4*)src;
            }
        }
        unsigned int* z = (unsigned int*)(lds + ZROW * RPB);
        for (int c = tid; c < RPB / 4; c += BLK) z[c] = 0u;
        for (int i = tid; i < 48 * CPITCH; i += BLK) clds[i] = 0.f;   // one-time
    }

    // ---- epilogue thread state (tid < 384): biases + register h_prev ----
    int eci = 0, eb = 0, elg = 0, ej = 0;
    float ebz = 0.f, ebr = 0.f, ebg = 0.f, ehp = 0.f;
    if (tid < NB * SLOTS) {
        eci = tid % SLOTS; eb = tid / SLOTS;
        const int slot = slot0 + eci;
        elg = slot >> 10; ej = slot & 1023;
        const size_t bidx = (size_t)elg * NH + ej;
        if (F32M) {
            ebz = ((const float*)bzh_)[bidx];
            ebr = ((const float*)brh_)[bidx];
            ebg = ((const float*)bgh_)[bidx];
        } else {
            ebz = bf2f(((const unsigned short*)bzh_)[bidx]);
            ebr = bf2f(((const unsigned short*)brh_)[bidx]);
            ebg = bf2f(((const unsigned short*)bgh_)[bidx]);
        }
    }

    // ---- layer groups (slot range may straddle one layer boundary) ----
    const int lay0 = slot0 >> 10;
    const int lay1 = (slot0 + SLOTS - 1) >> 10;
    const int ngroups = (lay0 == lay1) ? 1 : 2;
    const int n0 = (ngroups == 1) ? SLOTS : (1024 - (slot0 & 1023));

    const int myxcd = xcc_id();
    const bool isl0 = (lay0 == 0);
    const int mb = Mtile * 16 + n16;

    // x prefetch registers (phase-0 A-frags for layer-0 groups)
    short8 XH[8], XL[8];
    auto xprefetch = [&](int t) {
        if (F32M) {
            const float* xb = (const float*)x + ((size_t)mb * NS + t) * NI + khalf * 256 + q4 * 8;
#pragma unroll
            for (int ks = 0; ks < 8; ++ks) {
                float f[8];
                load8f(xb + ks * 32, f);
#pragma unroll
                for (int e = 0; e < 8; ++e) {
                    unsigned short h = f2bf(f[e]);
                    XH[ks][e] = (short)h;
                    XL[ks][e] = (short)f2bf(f[e] - bf2f(h));
                }
            }
        } else {
            const unsigned short* xb = (const unsigned short*)x + ((size_t)mb * NS + t) * NI + khalf * 256 + q4 * 8;
#pragma unroll
            for (int ks = 0; ks < 8; ++ks)
                XH[ks] = *(const short8*)(xb + ks * 32);
        }
    };
    if (isl0) xprefetch(0);

    __syncthreads();

    for (int s = 0; s < NS + NL - 1; ++s) {
        floatx4 acc[3];
#pragma unroll
        for (int nt = 0; nt < 3; ++nt) acc[nt] = (floatx4){0.f, 0.f, 0.f, 0.f};

        for (int grp = 0; grp < ngroups; ++grp) {
            const int lg = (grp == 0) ? lay0 : lay1;
            const int t = s - lg;
            if (t < 0 || t >= NS) continue;
            const int ntLo = (grp == 0) ? 0 : ((4 * n0) >> 4);
            const int ntHi = (grp == 0) ? (ngroups == 1 ? 2 : ((4 * n0) >> 4) - 1) : 2;

            for (int phase = 0; phase < 2; ++phase) {
                int brow[3];
#pragma unroll
                for (int nt = 0; nt < 3; ++nt) {
                    const int v = nt * 16 + n16;
                    const int ci = v >> 2, g = v & 3;
                    int r;
                    if (phase == 0) r = (g == 3) ? ZROW : ci * 6 + ((g == 2) ? 4 : g * 2);
                    else            r = (g == 2) ? ZROW : ci * 6 + ((g == 3) ? 5 : g * 2 + 1);
                    brow[nt] = r;
                }

                const bool isx = (phase == 0 && lg == 0);
                const bool dolo = isx ? (F32M != 0) : true;

                short8 AH[8], AL[8];
                if (isx) {
                    // prefetched during previous barrier window
#pragma unroll
                    for (int ks = 0; ks < 8; ++ks) { AH[ks] = XH[ks]; if (F32M) AL[ks] = XL[ks]; }
                } else {
                    const int src_l = (phase == 0) ? lg - 1 : lg;
                    const int src_p = (phase == 0) ? (t & 1) : ((t - 1) & 1);
                    const size_t ab = ((size_t)(src_l * 2 + src_p) * NB + mb) * NH + khalf * 256 + q4 * 8;
                    // PLAIN cached loads (L1/L2); coherence via the per-step
                    // per-XCD inv after the barrier below.
                    const uint4* ap = (const uint4*)(act + ab);
                    uint4 qq[16];
#pragma unroll
                    for (int ks = 0; ks < 8; ++ks) {
                        qq[2*ks]   = ap[ks * 8];
                        qq[2*ks+1] = ap[ks * 8 + 1];
                    }
#pragma unroll
                    for (int ks = 0; ks < 8; ++ks) {
                        unsigned int c[8] = {qq[2*ks].x, qq[2*ks].y, qq[2*ks].z, qq[2*ks].w,
                                             qq[2*ks+1].x, qq[2*ks+1].y, qq[2*ks+1].z, qq[2*ks+1].w};
#pragma unroll
                        for (int e = 0; e < 8; ++e) {
                            AH[ks][e] = (short)(c[e] >> 16);
                            AL[ks][e] = (short)(c[e] & 0xffffu);
                        }
                    }
                }

#pragma unroll
                for (int ks = 0; ks < 8; ++ks) {
                    const int k0 = khalf * 256 + ks * 32;
#pragma unroll
                    for (int nt = 0; nt < 3; ++nt) {
                        if (nt < ntLo || nt > ntHi) continue;
                        const short8 bf = *(const short8*)(lds + brow[nt] * RPB + k0 * 2 + q4 * 16);
                        acc[nt] = __builtin_amdgcn_mfma_f32_16x16x32_bf16(AH[ks], bf, acc[nt], 0, 0, 0);
                        if (dolo)
                            acc[nt] = __builtin_amdgcn_mfma_f32_16x16x32_bf16(AL[ks], bf, acc[nt], 0, 0, 0);
                    }
                }
            }
        }

        // dump accumulators (C/D: col=lane&15, row=q4*4+reg)
        {
            const int mbase = Mtile * 16 + q4 * 4;
#pragma unroll
            for (int nt = 0; nt < 3; ++nt) {
                const int vcol = nt * 16 + n16;
#pragma unroll
                for (int r = 0; r < 4; ++r)
                    atomicAdd(&clds[vcol * CPITCH + mbase + r], acc[nt][r]);
            }
        }
        __syncthreads();

        // epilogue: one thread per (col, batch); read-then-zero its 4 slots
        if (tid < NB * SLOTS) {
            const int t = s - elg;
            if (t >= 0 && t < NS) {
                const float zp = clds[(eci * 4 + 0) * CPITCH + eb];
                const float rp = clds[(eci * 4 + 1) * CPITCH + eb];
                const float gi = clds[(eci * 4 + 2) * CPITCH + eb];
                const float gh = clds[(eci * 4 + 3) * CPITCH + eb];
                clds[(eci * 4 + 0) * CPITCH + eb] = 0.f;
                clds[(eci * 4 + 1) * CPITCH + eb] = 0.f;
                clds[(eci * 4 + 2) * CPITCH + eb] = 0.f;
                clds[(eci * 4 + 3) * CPITCH + eb] = 0.f;
                float hp;
                if (t == 0) {
                    const size_t hoff = ((size_t)(elg * 2 + 1) * NB + eb) * NH + ej;
                    const unsigned int pv = act[hoff];   // init_act wrote it pre-kernel
                    hp = bf2f((unsigned short)(pv >> 16)) + bf2f((unsigned short)(pv & 0xffffu));
                } else {
                    hp = ehp;
                }
                const float z = 1.f / (1.f + expf(-(zp + ebz)));
                const float r = 1.f / (1.f + expf(-(rp + ebr)));
                const float g = tanhf(gi + r * (gh + ebg));
                const float hn = z * hp + (1.f - z) * g;
                ehp = hn;
                const unsigned short hi = f2bf(hn);
                const unsigned short lo = f2bf(hn - bf2f(hi));
                const size_t woff = ((size_t)(elg * 2 + (t & 1)) * NB + eb) * NH + ej;
                // sc1 write-through store: lands in L3, never dirty in L2
                __hip_atomic_store(&act[woff], ((unsigned int)hi << 16) | lo,
                                   __ATOMIC_RELAXED, __HIP_MEMORY_SCOPE_AGENT);
                if (elg == 2) {
                    const size_t o = ((size_t)eb * NS + t) * NO + ej;
                    if (F32M) ((float*)dout)[o] = hn;
                    else      ((unsigned short*)dout)[o] = f2bf(hn);
                }
                if (t == NS - 1)
                    stfin[((size_t)elg * NB + eb) * NH + ej] = hn;
            }
        }

        // ---- barrier: arrival -> (x prefetch overlap) -> master/gen -> inv
        __syncthreads();   // drains each wave's sc1 stores (vmcnt 0) before publish
        if (tid == 0)
            __hip_atomic_store(&gflags[wg * 32], (unsigned int)(s + 1),
                               __ATOMIC_RELAXED, __HIP_MEMORY_SCOPE_AGENT);

        // overlap next-step x load+convert with the barrier hops (x read-only)
        if (isl0 && (s + 1) < NS) xprefetch(s + 1);

        if (wg == 0) {
            // master: 4 waves poll all 256 per-WG flags (1 lane : 1 flag)
            if (tid < WGN) {
                while (__hip_atomic_load(&gflags[tid * 32], __ATOMIC_RELAXED,
                                         __HIP_MEMORY_SCOPE_AGENT) <= (unsigned int)s)
                    __builtin_amdgcn_s_sleep(1);
            }
            __syncthreads();   // all 256 arrivals observed
            if (tid < 16)      // broadcast tree: 16 gen copies, <=16 pollers each
                __hip_atomic_store(&gflags[GENB + tid * 32], (unsigned int)(s + 1),
                                   __ATOMIC_RELAXED, __HIP_MEMORY_SCOPE_AGENT);
        } else {
            if (tid == 0) {
                while (__hip_atomic_load(&gflags[GENB + (wg >> 4) * 32], __ATOMIC_RELAXED,
                                         __HIP_MEMORY_SCOPE_AGENT) <= (unsigned int)s)
                    __builtin_amdgcn_s_sleep(1);
            }
        }
        // per-XCD single L2 inv; everyone flash-invs their own CU's L1
        if (tid == 0) {
            const unsigned tag = (unsigned)(s + 1);
            unsigned* claim = &gflags[CLAIMB + (myxcd * 2 + (s & 1)) * 32];
            unsigned old = __hip_atomic_exchange(claim, tag,
                                                 __ATOMIC_RELAXED, __HIP_MEMORY_SCOPE_AGENT);
            if (old != tag) {
                // winner: full acquire (waits + L1 inv + this XCD's L2 inv)
                __builtin_amdgcn_fence(__ATOMIC_ACQUIRE, "agent");
                __hip_atomic_store(&gflags[DONEB + myxcd * 32], tag,
                                   __ATOMIC_RELAXED, __HIP_MEMORY_SCOPE_AGENT);
            } else {
                // loser: wait for winner's L2 inv, then L1-only flash inv
                while (__hip_atomic_load(&gflags[DONEB + myxcd * 32], __ATOMIC_RELAXED,
                                         __HIP_MEMORY_SCOPE_AGENT) <= (unsigned int)s)
                    __builtin_amdgcn_s_sleep(1);
                asm volatile("buffer_inv" ::: "memory");
            }
            __builtin_amdgcn_sched_barrier(0);
        }
        __syncthreads();   // no wave issues next-step loads before tid0's inv
    }
}

// ---------------- fallback kernels (round-2, proven) ----------------
__global__ void init_kernel(const void* __restrict__ h0, float* __restrict__ st,
                            const int* __restrict__ flagp) {
    const int f32m = *flagp;
    const int idx = blockIdx.x * 256 + threadIdx.x;
    if (idx >= NL * NB * NH) return;
    const int l = idx >> 15;
    const int b = (idx >> 10) & 31;
    const int j = idx & 1023;
    const size_t src = (size_t)b * NL * NH + (size_t)l * NH + j;
    st[idx] = f32m ? ((const float*)h0)[src] : bf2f(((const unsigned short*)h0)[src]);
}

__global__ __launch_bounds__(256) void gru_layer(
    const void*  __restrict__ x,
    const float* __restrict__ inp,
    const float* __restrict__ hprev,
    float*       __restrict__ hnew,
    void*        __restrict__ h2out,
    const void* __restrict__ Wzi_, const void* __restrict__ Wzh_, const void* __restrict__ bzh_,
    const void* __restrict__ Wri_, const void* __restrict__ Wrh_, const void* __restrict__ brh_,
    const void* __restrict__ Wgi_, const void* __restrict__ Wgh_, const void* __restrict__ bgh_,
    const int* __restrict__ flagp, int tl, int isX)
{
    __shared__ float s_in[NB][129];
    __shared__ float s_h [NB][129];
    __shared__ float s_red[256][6];

    const int f32m = *flagp;
    const int t = tl & 0xFFFF;
    const int l = tl >> 16;
    const int tid = threadIdx.x;
    const int b   = tid & 31;
    const int jl  = (tid >> 5) & 1;
    const int ks  = tid >> 6;
    const int j   = blockIdx.x * 2 + jl;

    const size_t wIl = (size_t)l * NH * NI + (size_t)j * NI;
    const size_t bl  = (size_t)l * NH + j;

    float azi = 0.f, azh = 0.f, ari = 0.f, arh = 0.f, agi = 0.f, agh = 0.f;

    for (int kc = 0; kc < 8; ++kc) {
        const int k0 = kc * 128;
        __syncthreads();
        for (int idx = tid; idx < NB * 128; idx += 256) {
            const int r = idx >> 7, c = idx & 127;
            float vi;
            if (isX) {
                const size_t xo = (size_t)r * NS * NI + (size_t)t * NI + (k0 + c);
                vi = f32m ? ((const float*)x)[xo] : bf2f(((const unsigned short*)x)[xo]);
            } else {
                vi = inp[r * NH + k0 + c];
            }
            s_in[r][c] = vi;
            s_h [r][c] = hprev[r * NH + k0 + c];
        }
        __syncthreads();

        const int cbase = ks * 32;
#pragma unroll
        for (int q8 = 0; q8 < 4; ++q8) {
            const int c = cbase + q8 * 8;
            const int k = k0 + c;
            float wz[8], wr[8], wg[8], vz[8], vr[8], vg[8];
            if (f32m) {
                load8f((const float*)Wzi_ + wIl + k, wz);
                load8f((const float*)Wri_ + wIl + k, wr);
                load8f((const float*)Wgi_ + wIl + k, wg);
                load8f((const float*)Wzh_ + wIl + k, vz);
                load8f((const float*)Wrh_ + wIl + k, vr);
                load8f((const float*)Wgh_ + wIl + k, vg);
            } else {
                load8h((const unsigned short*)Wzi_ + wIl + k, wz);
                load8h((const unsigned short*)Wri_ + wIl + k, wr);
                load8h((const unsigned short*)Wgi_ + wIl + k, wg);
                load8h((const unsigned short*)Wzh_ + wIl + k, vz);
                load8h((const unsigned short*)Wrh_ + wIl + k, vr);
                load8h((const unsigned short*)Wgh_ + wIl + k, vg);
            }
            float ai[8], ah[8];
#pragma unroll
            for (int q = 0; q < 8; ++q) { ai[q] = s_in[b][c + q]; ah[q] = s_h[b][c + q]; }
#pragma unroll
            for (int q = 0; q < 8; ++q) {
                azi = fmaf(wz[q], ai[q], azi);
                ari = fmaf(wr[q], ai[q], ari);
                agi = fmaf(wg[q], ai[q], agi);
                azh = fmaf(vz[q], ah[q], azh);
                arh = fmaf(vr[q], ah[q], arh);
                agh = fmaf(vg[q], ah[q], agh);
            }
        }
    }

    s_red[tid][0] = azi; s_red[tid][1] = azh; s_red[tid][2] = ari;
    s_red[tid][3] = arh; s_red[tid][4] = agi; s_red[tid][5] = agh;
    __syncthreads();

    if (ks == 0) {
#pragma unroll
        for (int w = 1; w < 4; ++w) {
            azi += s_red[tid + 64*w][0]; azh += s_red[tid + 64*w][1];
            ari += s_red[tid + 64*w][2]; arh += s_red[tid + 64*w][3];
            agi += s_red[tid + 64*w][4]; agh += s_red[tid + 64*w][5];
        }
        const float bz = f32m ? ((const float*)bzh_)[bl] : bf2f(((const unsigned short*)bzh_)[bl]);
        const float br = f32m ? ((const float*)brh_)[bl] : bf2f(((const unsigned short*)brh_)[bl]);
        const float bg = f32m ? ((const float*)bgh_)[bl] : bf2f(((const unsigned short*)bgh_)[bl]);
        const float z = 1.f / (1.f + expf(-(azi + azh + bz)));
        const float r = 1.f / (1.f + expf(-(ari + arh + br)));
        const float g = tanhf(agi + r * (agh + bg));
        const float hp = hprev[b * NH + j];
        const float hn = z * hp + (1.f - z) * g;
        hnew[b * NH + j] = hn;
        if (h2out) {
            const size_t off = (size_t)b * NS * NO + (size_t)t * NO + j;
            if (f32m) ((float*)h2out)[off] = hn;
            else      ((unsigned short*)h2out)[off] = f2bf(hn);
        }
    }
}

__global__ __launch_bounds__(256) void out_gemm(
    void* __restrict__ out, const void* __restrict__ Wout, const void* __restrict__ bout,
    const int* __restrict__ flagp)
{
    __shared__ float s_a[8][1024];
    const int f32m = *flagp;
    const int tid = threadIdx.x;
    const size_t row0 = (size_t)blockIdx.x * 8;

    for (int idx = tid; idx < 8 * 1024; idx += 256) {
        const int r = idx >> 10, c = idx & 1023;
        const size_t off = (row0 + r) * NO + c;
        s_a[r][c] = f32m ? ((const float*)out)[off] : bf2f(((const unsigned short*)out)[off]);
    }
    __syncthreads();

    float acc[4][8];
#pragma unroll
    for (int m = 0; m < 4; ++m)
#pragma unroll
        for (int r = 0; r < 8; ++r) acc[m][r] = 0.f;

    for (int k8 = 0; k8 < 128; ++k8) {
        const int k = k8 * 8;
        float wf[4][8];
#pragma unroll
        for (int m = 0; m < 4; ++m) {
            const size_t wo = (size_t)(tid + 256*m) * NH + k;
            if (f32m) load8f((const float*)Wout + wo, wf[m]);
            else      load8h((const unsigned short*)Wout + wo, wf[m]);
        }
#pragma unroll
        for (int r = 0; r < 8; ++r) {
            float a[8];
#pragma unroll
            for (int q = 0; q < 8; ++q) a[q] = s_a[r][k + q];
#pragma unroll
            for (int m = 0; m < 4; ++m)
#pragma unroll
                for (int q = 0; q < 8; ++q)
                    acc[m][r] = fmaf(wf[m][q], a[q], acc[m][r]);
        }
    }

#pragma unroll
    for (int m = 0; m < 4; ++m) {
        const int jj = tid + 256*m;
        const float bj = f32m ? ((const float*)bout)[jj] : bf2f(((const unsigned short*)bout)[jj]);
#pragma unroll
        for (int r = 0; r < 8; ++r) {
            const size_t off = (row0 + r) * NO + jj;
            const float v = acc[m][r] + bj;
            if (f32m) ((float*)out)[off] = v;
            else      ((unsigned short*)out)[off] = f2bf(v);
        }
    }
}

__global__ void tail_kernel(const float* __restrict__ st, void* __restrict__ out,
                            const int* __restrict__ flagp)
{
    const int f32m = *flagp;
    const int idx = blockIdx.x * 256 + threadIdx.x;
    if (idx >= NL * NB * NH) return;
    const int l = idx >> 15;
    const int b = (idx >> 10) & 31;
    const int j = idx & 1023;
    const size_t dst = (size_t)NB * NS * NO + (size_t)b * NL * NH + (size_t)l * NH + j;
    if (f32m) ((float*)out)[dst] = st[idx];
    else      ((unsigned short*)out)[dst] = f2bf(st[idx]);
}

// ---------------- host ----------------
extern "C" void kernel_launch(void* const* d_in, const int* in_sizes, int n_in,
                              void* d_out, int out_size, void* d_ws, size_t ws_size,
                              hipStream_t stream)
{
    const void* x    = d_in[0];
    const void* h0   = d_in[1];
    const void* Wzi  = d_in[2];
    const void* Wzh  = d_in[3];
    const void* bzh  = d_in[4];
    const void* Wri  = d_in[5];
    const void* Wrh  = d_in[6];
    const void* brh  = d_in[7];
    const void* Wgi  = d_in[8];
    const void* Wgh  = d_in[9];
    const void* bgh  = d_in[10];
    const void* Wout = d_in[11];
    const void* bout = d_in[12];

    // ws layout
    char* w = (char*)d_ws;
    float* st            = (float*)w;                       // [2][3][32][1024] f32
    int*   flag          = (int*)(w + 786432);
    unsigned int* act    = (unsigned int*)(w + 786464);     // [3][2][32][1024] packed hi|lo
    unsigned int* gflags = (unsigned int*)(w + 1572992);    // GFL_N dwords
    auto stp = [&](int p, int l) { return st + ((size_t)(p * NL + l)) * NB * NH; };

    detect_kernel<<<1, 256, 0, stream>>>((const unsigned int*)x, flag);
    init_act<<<(NL*NB*NH + 255)/256, 256, 0, stream>>>(h0, act, gflags, flag);

    (void)hipFuncSetAttribute((const void*)&gru_persist<1>,
                              hipFuncAttributeMaxDynamicSharedMemorySize, LDSB);
    (void)hipFuncSetAttribute((const void*)&gru_persist<0>,
                              hipFuncAttributeMaxDynamicSharedMemorySize, LDSB);
    (void)hipGetLastError();   // clear
    gru_persist<1><<<WGN, BLK, LDSB, stream>>>(
        x, Wzi, Wzh, bzh, Wri, Wrh, brh, Wgi, Wgh, bgh,
        d_out, act, st, flag, gflags);
    gru_persist<0><<<WGN, BLK, LDSB, stream>>>(
        x, Wzi, Wzh, bzh, Wri, Wrh, brh, Wgi, Wgh, bgh,
        d_out, act, st, flag, gflags);
    hipError_t perr = hipGetLastError();

    if (perr != hipSuccess) {
        init_kernel<<<(NL*NB*NH + 255)/256, 256, 0, stream>>>(h0, st, flag);
        for (int t = 0; t < NS; ++t) {
            const int pr = t & 1, pw = 1 - pr;
            for (int l = 0; l < NL; ++l) {
                gru_layer<<<512, 256, 0, stream>>>(
                    x,
                    l == 0 ? st : stp(pw, l - 1),
                    stp(pr, l),
                    stp(pw, l),
                    l == 2 ? d_out : (void*)nullptr,
                    Wzi, Wzh, bzh, Wri, Wrh, brh, Wgi, Wgh, bgh,
                    flag, t | (l << 16), l == 0 ? 1 : 0);
            }
        }
    }

    out_gemm<<<NB * NS / 8, 256, 0, stream>>>(d_out, Wout, bout, flag);
    tail_kernel<<<(NL*NB*NH + 255)/256, 256, 0, stream>>>(st, d_out, flag);
}